// Round 2
// baseline (102586.438 us; speedup 1.0000x reference)
//
#include <hip/hip_runtime.h>
#include <math.h>

#define NSMP 48

__device__ __forceinline__ float gelu_f(float x){
    return 0.5f*x*(1.0f+erff(x*0.70710678118654752f));
}

// scheduling fence: global/LDS memory ops cannot cross, pinning phase live-ranges
#define PHASE_FENCE() asm volatile("" ::: "memory")

template<bool TR>
__global__ __launch_bounds__(256)
void render_kernel(const float* __restrict__ rays_o,
                   const float* __restrict__ rays_d,
                   const float* __restrict__ mats,
                   const float* __restrict__ vecs,
                   const float* __restrict__ g_wmat, const float* __restrict__ g_bmat,
                   const float* __restrict__ g_w1,  const float* __restrict__ g_b1,
                   const float* __restrict__ g_w2,  const float* __restrict__ g_b2,
                   float* __restrict__ out, int B, int R)
{
    __shared__ __align__(16) float s_wmat[72*64];
    __shared__ __align__(16) float s_w1[91*64];
    __shared__ __align__(16) float s_bmat[64];
    __shared__ __align__(16) float s_b1[64];
    __shared__ float s_w2[64*3];
    __shared__ float s_b2[3];

    const int tid = threadIdx.x;
    for (int i=tid;i<72*64;i+=256) s_wmat[i]=g_wmat[i];
    for (int i=tid;i<91*64;i+=256) s_w1[i]=g_w1[i];
    if (tid<64){ s_bmat[tid]=g_bmat[tid]; s_b1[tid]=g_b1[tid]; }
    if (tid<192) s_w2[tid]=g_w2[tid];
    if (tid<3)  s_b2[tid]=g_b2[tid];
    __syncthreads();

    const int lane = tid & 63;
    const int ray  = blockIdx.x*4 + (tid>>6);
    const int NR   = B*R;
    if (ray >= NR) return;
    const int b    = ray / R;

    const float ox=rays_o[ray*3+0], oy=rays_o[ray*3+1], oz=rays_o[ray*3+2];
    const float dx=rays_d[ray*3+0], dy=rays_d[ray*3+1], dz=rays_d[ray*3+2];

    const int s = lane;
    const bool active = (s < NSMP);
    const float mid = ((float)s + 0.5f) * 0.03125f;   // (FAR-NEAR)/NS = 1.5/48

    // xyz = (pts+0.8)*1.25-1 = 1.25*pts
    const float x0c = 1.25f*(ox + dx*mid);
    const float x1c = 1.25f*(oy + dy*mid);
    const float x2c = 1.25f*(oz + dz*mid);

    // ---------------- Phase A: gather 72 rgb features + sigma ----------------
    float f[72];
    float sigma = 0.0f;

    #pragma unroll
    for (int i=0;i<3;i++){
        // MAT_MODE = {{0,1},{2,0},{1,2}}, VEC_MODE = {2,1,0}
        const float cx = (i==0)? x0c : (i==1)? x2c : x1c;
        const float cy = (i==0)? x1c : (i==1)? x0c : x2c;
        const float cv = (i==0)? x2c : (i==1)? x1c : x0c;

        const float px = (cx+1.0f)*23.5f;   // 0.5*(48-1)
        const float py = (cy+1.0f)*23.5f;
        const float fx0 = floorf(px), fy0 = floorf(py);
        const float wx = px-fx0, wy = py-fy0;
        const int ix0 = (int)fx0, iy0 = (int)fy0;

        int   toff[4];
        float tw[4];
        #pragma unroll
        for (int t=0;t<4;t++){
            const int xx = ix0 + (t&1);
            const int yy = iy0 + (t>>1);
            const bool inb = (xx>=0)&&(xx<48)&&(yy>=0)&&(yy<48);
            const int xcl = min(max(xx,0),47);
            const int ycl = min(max(yy,0),47);
            toff[t] = ycl*48+xcl;
            const float wxx = (t&1)? wx : 1.0f-wx;
            const float wyy = (t>>1)? wy : 1.0f-wy;
            tw[t] = inb ? wxx*wyy : 0.0f;
        }

        const float pv = (cv+1.0f)*23.5f;
        const float fp0 = floorf(pv);
        const float wv = pv-fp0;
        const int ip0 = (int)fp0;
        int voff[2]; float vw[2];
        #pragma unroll
        for (int t=0;t<2;t++){
            const int pp = ip0+t;
            const bool inb = (pp>=0)&&(pp<48);
            voff[t] = min(max(pp,0),47);
            vw[t] = inb ? ((t)? wv : 1.0f-wv) : 0.0f;
        }

        if (TR){
            // channel-last layout: [ib][pix][32] and [ib][r][32]
            const float* pb = mats + ((size_t)(i*B+b))*(2304u*32u);
            const float* vb = vecs + ((size_t)(i*B+b))*(48u*32u);
            const float4* t0 = (const float4*)(pb + toff[0]*32);
            const float4* t1 = (const float4*)(pb + toff[1]*32);
            const float4* t2 = (const float4*)(pb + toff[2]*32);
            const float4* t3 = (const float4*)(pb + toff[3]*32);
            const float4* v0 = (const float4*)(vb + voff[0]*32);
            const float4* v1 = (const float4*)(vb + voff[1]*32);
            #pragma unroll
            for (int c4=0;c4<8;c4++){
                const float4 a0=t0[c4], a1=t1[c4], a2=t2[c4], a3=t3[c4];
                const float4 q0=v0[c4], q1=v1[c4];
                float r0,r1,r2,r3;
                r0 = (tw[0]*a0.x+tw[1]*a1.x+tw[2]*a2.x+tw[3]*a3.x)*(vw[0]*q0.x+vw[1]*q1.x);
                r1 = (tw[0]*a0.y+tw[1]*a1.y+tw[2]*a2.y+tw[3]*a3.y)*(vw[0]*q0.y+vw[1]*q1.y);
                r2 = (tw[0]*a0.z+tw[1]*a1.z+tw[2]*a2.z+tw[3]*a3.z)*(vw[0]*q0.z+vw[1]*q1.z);
                r3 = (tw[0]*a0.w+tw[1]*a1.w+tw[2]*a2.w+tw[3]*a3.w)*(vw[0]*q0.w+vw[1]*q1.w);
                if (c4 < 2){
                    sigma += r0 + r1 + r2 + r3;
                } else {
                    f[i*24 + c4*4 - 8 + 0] = r0;
                    f[i*24 + c4*4 - 8 + 1] = r1;
                    f[i*24 + c4*4 - 8 + 2] = r2;
                    f[i*24 + c4*4 - 8 + 3] = r3;
                }
            }
        } else {
            // original layout: [ib][c][2304] and [ib][c][48]
            const float* pb = mats + ((size_t)(i*B+b))*(32u*2304u);
            const float* vb = vecs + ((size_t)(i*B+b))*(32u*48u);
            #pragma unroll
            for (int c=0;c<32;c++){
                const float* fc = pb + c*2304;
                const float pf = tw[0]*fc[toff[0]] + tw[1]*fc[toff[1]]
                               + tw[2]*fc[toff[2]] + tw[3]*fc[toff[3]];
                const float* vc = vb + c*48;
                const float vf = vw[0]*vc[voff[0]] + vw[1]*vc[voff[1]];
                const float r = pf*vf;
                if (c < 8) sigma += r;
                else       f[i*24 + c - 8] = r;
            }
        }
    }

    PHASE_FENCE();

    // ---------------- Phase B: gelu on features ----------------
    #pragma unroll
    for (int k=0;k<72;k++) f[k] = gelu_f(f[k]);

    PHASE_FENCE();

    // ---------------- Phase C: hid[64] = g @ w_mat + b_mat ----------------
    float hid[64];
    {
        const float4* bb = (const float4*)s_bmat;
        #pragma unroll
        for (int j=0;j<16;j++){
            const float4 v = bb[j];
            hid[4*j+0]=v.x; hid[4*j+1]=v.y; hid[4*j+2]=v.z; hid[4*j+3]=v.w;
        }
    }
    #pragma unroll
    for (int k=0;k<72;k++){
        const float v = f[k];
        const float4* wr = (const float4*)(s_wmat + k*64);
        #pragma unroll
        for (int j=0;j<16;j++){
            const float4 w = wr[j];
            hid[4*j+0]+=v*w.x; hid[4*j+1]+=v*w.y; hid[4*j+2]+=v*w.z; hid[4*j+3]+=v*w.w;
        }
    }

    PHASE_FENCE();

    // layer-1 activation
    #pragma unroll
    for (int j=0;j<64;j++) hid[j] = gelu_f(hid[j]);

    // view-dir positional encoding (wave-uniform per ray)
    const float inv_n = rsqrtf(dx*dx+dy*dy+dz*dz);
    const float vdx = dx*inv_n, vdy = dy*inv_n, vdz = dz*inv_n;
    float vdpe[27];
    vdpe[0]=vdx; vdpe[1]=vdy; vdpe[2]=vdz;
    #pragma unroll
    for (int fq=0;fq<4;fq++){
        const float fs = (float)(1<<fq);
        vdpe[3+fq*3+0]  = sinf(vdx*fs);
        vdpe[3+fq*3+1]  = sinf(vdy*fs);
        vdpe[3+fq*3+2]  = sinf(vdz*fs);
        vdpe[15+fq*3+0] = cosf(vdx*fs);
        vdpe[15+fq*3+1] = cosf(vdy*fs);
        vdpe[15+fq*3+2] = cosf(vdz*fs);
    }

    PHASE_FENCE();

    // ---------------- Phase D: layer 2 (91 -> 64 in two halves) + layer 3 ----------------
    float rgb0=s_b2[0], rgb1=s_b2[1], rgb2=s_b2[2];
    #pragma unroll
    for (int half=0; half<2; half++){
        float h2[32];
        #pragma unroll
        for (int j=0;j<32;j++) h2[j] = s_b1[half*32+j];
        #pragma unroll
        for (int k=0;k<64;k++){
            const float v = hid[k];
            const float4* wr = (const float4*)(s_w1 + k*64 + half*32);
            #pragma unroll
            for (int j=0;j<8;j++){
                const float4 w = wr[j];
                h2[4*j+0]+=v*w.x; h2[4*j+1]+=v*w.y; h2[4*j+2]+=v*w.z; h2[4*j+3]+=v*w.w;
            }
        }
        #pragma unroll
        for (int k=0;k<27;k++){
            const float v = vdpe[k];
            const float4* wr = (const float4*)(s_w1 + (64+k)*64 + half*32);
            #pragma unroll
            for (int j=0;j<8;j++){
                const float4 w = wr[j];
                h2[4*j+0]+=v*w.x; h2[4*j+1]+=v*w.y; h2[4*j+2]+=v*w.z; h2[4*j+3]+=v*w.w;
            }
        }
        #pragma unroll
        for (int j=0;j<32;j++){
            const float g = gelu_f(h2[j]);
            const int jj = half*32+j;
            rgb0 += g*s_w2[jj*3+0];
            rgb1 += g*s_w2[jj*3+1];
            rgb2 += g*s_w2[jj*3+2];
        }
    }
    rgb0 = 1.0f/(1.0f+expf(-rgb0));
    rgb1 = 1.0f/(1.0f+expf(-rgb1));
    rgb2 = 1.0f/(1.0f+expf(-rgb2));

    // ---------------- Phase E: volume integration (lane product scan) ----------------
    const float sg = fmaxf(sigma, 0.0f);
    const float alpha = active ? (1.0f - expf(-sg*0.03125f)) : 0.0f;
    float v = active ? (1.0f - alpha + 1e-10f) : 1.0f;
    #pragma unroll
    for (int off=1; off<64; off<<=1){
        const float up = __shfl_up(v, off, 64);
        if (lane >= off) v *= up;
    }
    float T = __shfl_up(v, 1, 64);
    if (lane==0) T = 1.0f;
    const float w = active ? alpha*T : 0.0f;

    if (active) out[(size_t)NR*4 + (size_t)ray*NSMP + s] = w;

    float a0=w*rgb0, a1=w*rgb1, a2=w*rgb2, ad=w*mid;
    #pragma unroll
    for (int off=32; off>0; off>>=1){
        a0 += __shfl_down(a0, off, 64);
        a1 += __shfl_down(a1, off, 64);
        a2 += __shfl_down(a2, off, 64);
        ad += __shfl_down(ad, off, 64);
    }
    if (lane==0){
        out[(size_t)ray*3+0]=a0;
        out[(size_t)ray*3+1]=a1;
        out[(size_t)ray*3+2]=a2;
        out[(size_t)NR*3 + (size_t)ray]=ad;
    }
}

__global__ void transpose_mats(const float* __restrict__ in, float* __restrict__ out, int total){
    const int idx = blockIdx.x*blockDim.x+threadIdx.x;
    if (idx < total){
        const int pix = idx % 2304;
        const int c   = (idx / 2304) & 31;
        const int ib  = idx / (2304*32);
        out[((size_t)ib*2304+pix)*32 + c] = in[idx];
    }
}

__global__ void transpose_vecs(const float* __restrict__ in, float* __restrict__ out, int total){
    const int idx = blockIdx.x*blockDim.x+threadIdx.x;
    if (idx < total){
        const int r  = idx % 48;
        const int c  = (idx / 48) & 31;
        const int ib = idx / (48*32);
        out[((size_t)ib*48+r)*32 + c] = in[idx];
    }
}

extern "C" void kernel_launch(void* const* d_in, const int* in_sizes, int n_in,
                              void* d_out, int out_size, void* d_ws, size_t ws_size,
                              hipStream_t stream) {
    const float* rays_o  = (const float*)d_in[0];
    const float* rays_d  = (const float*)d_in[1];
    const float* matrixs = (const float*)d_in[2];
    const float* vectors = (const float*)d_in[3];
    const float* w_mat   = (const float*)d_in[4];
    const float* b_mat   = (const float*)d_in[5];
    const float* w1      = (const float*)d_in[6];
    const float* b1      = (const float*)d_in[7];
    const float* w2      = (const float*)d_in[8];
    const float* b2      = (const float*)d_in[9];
    float* out = (float*)d_out;

    const int B = in_sizes[2] / (3*32*48*48);
    const int R = (in_sizes[0]/3) / B;
    const int NR = B*R;

    const int matsz = 3*B*32*2304;
    const int vecsz = 3*B*32*48;
    const size_t need = ((size_t)matsz + (size_t)vecsz)*sizeof(float);

    const int nblk = (NR + 3)/4;
    if (ws_size >= need){
        float* tm = (float*)d_ws;
        float* tv = tm + matsz;
        transpose_mats<<<(matsz+255)/256, 256, 0, stream>>>(matrixs, tm, matsz);
        transpose_vecs<<<(vecsz+255)/256, 256, 0, stream>>>(vectors, tv, vecsz);
        render_kernel<true><<<nblk, 256, 0, stream>>>(rays_o, rays_d, tm, tv,
            w_mat, b_mat, w1, b1, w2, b2, out, B, R);
    } else {
        render_kernel<false><<<nblk, 256, 0, stream>>>(rays_o, rays_d, matrixs, vectors,
            w_mat, b_mat, w1, b1, w2, b2, out, B, R);
    }
}

// Round 3
// 2398.418 us; speedup vs baseline: 42.7725x; 42.7725x over previous
//
#include <hip/hip_runtime.h>
#include <math.h>

#define NSMP 48

__device__ __forceinline__ float gelu_f(float x){
    return 0.5f*x*(1.0f+erff(x*0.70710678118654752f));
}

// compiler scheduling fence (no memory op may cross)
#define MEM_FENCE() asm volatile("" ::: "memory")
// wave-synchronous LDS fence: drain all LDS ops, then fence the compiler
#define LDS_FENCE() asm volatile("s_waitcnt lgkmcnt(0)" ::: "memory")

template<bool TR>
__global__ __launch_bounds__(256)
void render_kernel(const float* __restrict__ rays_o,
                   const float* __restrict__ rays_d,
                   const float* __restrict__ mats,
                   const float* __restrict__ vecs,
                   const float* __restrict__ g_wmat, const float* __restrict__ g_bmat,
                   const float* __restrict__ g_w1,  const float* __restrict__ g_b1,
                   const float* __restrict__ g_w2,  const float* __restrict__ g_b2,
                   float* __restrict__ out, int B, int R)
{
    // per-wave LDS regions (no cross-wave sharing -> no __syncthreads anywhere)
    __shared__ __align__(16) float s_feat[4][NSMP*72];  // gelu'd rgb features
    __shared__ __align__(16) float s_hid [4][64];       // layer-1 output exchange
    __shared__ __align__(16) float s_rgb [4][NSMP*4];   // per-sample rgb (padded to 4)

    const int tid  = threadIdx.x;
    const int wv   = tid >> 6;
    const int lane = tid & 63;
    const int NR   = B*R;
    const int ray  = blockIdx.x*4 + wv;
    if (ray >= NR) return;           // wave-uniform exit
    const int b = ray / R;

    float* gF   = s_feat[wv];
    float* gH   = s_hid[wv];
    float* gRGB = s_rgb[wv];

    const float ox=rays_o[ray*3+0], oy=rays_o[ray*3+1], oz=rays_o[ray*3+2];
    const float dx=rays_d[ray*3+0], dy=rays_d[ray*3+1], dz=rays_d[ray*3+2];

    // ================= Phase 1: gather (lane = sample) =================
    const int  s      = lane;
    const bool active = (s < NSMP);
    const int  sc     = active ? s : (NSMP-1);
    const float mid   = ((float)s  + 0.5f) * 0.03125f;  // for depth (w=0 if inactive)
    const float midc  = ((float)sc + 0.5f) * 0.03125f;  // safe coords for idle lanes

    // xyz = (pts+0.8)*1.25-1 = 1.25*pts
    const float x0c = 1.25f*(ox + dx*midc);
    const float x1c = 1.25f*(oy + dy*midc);
    const float x2c = 1.25f*(oz + dz*midc);

    float sigma = 0.0f;

    #pragma unroll
    for (int i=0;i<3;i++){
        // MAT_MODE = {{0,1},{2,0},{1,2}}, VEC_MODE = {2,1,0}
        const float cx = (i==0)? x0c : (i==1)? x2c : x1c;
        const float cy = (i==0)? x1c : (i==1)? x0c : x2c;
        const float cv = (i==0)? x2c : (i==1)? x1c : x0c;

        const float px = (cx+1.0f)*23.5f;   // 0.5*(48-1)
        const float py = (cy+1.0f)*23.5f;
        const float fx0 = floorf(px), fy0 = floorf(py);
        const float wx = px-fx0, wy = py-fy0;
        const int ix0 = (int)fx0, iy0 = (int)fy0;

        int   toff[4];
        float tw[4];
        #pragma unroll
        for (int t=0;t<4;t++){
            const int xx = ix0 + (t&1);
            const int yy = iy0 + (t>>1);
            const bool inb = (xx>=0)&&(xx<48)&&(yy>=0)&&(yy<48);
            const int xcl = min(max(xx,0),47);
            const int ycl = min(max(yy,0),47);
            toff[t] = ycl*48+xcl;
            const float wxx = (t&1)? wx : 1.0f-wx;
            const float wyy = (t>>1)? wy : 1.0f-wy;
            tw[t] = inb ? wxx*wyy : 0.0f;
        }

        const float pv = (cv+1.0f)*23.5f;
        const float fp0 = floorf(pv);
        const float wvv = pv-fp0;
        const int ip0 = (int)fp0;
        int voff[2]; float vw[2];
        #pragma unroll
        for (int t=0;t<2;t++){
            const int pp = ip0+t;
            const bool inb = (pp>=0)&&(pp<48);
            voff[t] = min(max(pp,0),47);
            vw[t] = inb ? ((t)? wvv : 1.0f-wvv) : 0.0f;
        }

        if (TR){
            // channel-last layout: [ib][pix][32] and [ib][r][32]
            const float* pb = mats + ((size_t)(i*B+b))*(2304u*32u);
            const float* vb = vecs + ((size_t)(i*B+b))*(48u*32u);
            const float4* t0 = (const float4*)(pb + toff[0]*32);
            const float4* t1 = (const float4*)(pb + toff[1]*32);
            const float4* t2 = (const float4*)(pb + toff[2]*32);
            const float4* t3 = (const float4*)(pb + toff[3]*32);
            const float4* v0 = (const float4*)(vb + voff[0]*32);
            const float4* v1 = (const float4*)(vb + voff[1]*32);
            #pragma unroll
            for (int c4=0;c4<8;c4++){
                const float4 a0=t0[c4], a1=t1[c4], a2=t2[c4], a3=t3[c4];
                const float4 q0=v0[c4], q1=v1[c4];
                float r0,r1,r2,r3;
                r0 = (tw[0]*a0.x+tw[1]*a1.x+tw[2]*a2.x+tw[3]*a3.x)*(vw[0]*q0.x+vw[1]*q1.x);
                r1 = (tw[0]*a0.y+tw[1]*a1.y+tw[2]*a2.y+tw[3]*a3.y)*(vw[0]*q0.y+vw[1]*q1.y);
                r2 = (tw[0]*a0.z+tw[1]*a1.z+tw[2]*a2.z+tw[3]*a3.z)*(vw[0]*q0.z+vw[1]*q1.z);
                r3 = (tw[0]*a0.w+tw[1]*a1.w+tw[2]*a2.w+tw[3]*a3.w)*(vw[0]*q0.w+vw[1]*q1.w);
                if (c4 < 2){
                    sigma += r0 + r1 + r2 + r3;
                } else if (active){
                    float4 gv;
                    gv.x=gelu_f(r0); gv.y=gelu_f(r1); gv.z=gelu_f(r2); gv.w=gelu_f(r3);
                    *(float4*)(gF + s*72 + i*24 + c4*4 - 8) = gv;
                }
            }
        } else {
            // original layout: [ib][c][2304] and [ib][c][48]
            const float* pb = mats + ((size_t)(i*B+b))*(32u*2304u);
            const float* vb = vecs + ((size_t)(i*B+b))*(32u*48u);
            #pragma unroll
            for (int c=0;c<32;c++){
                const float* fc = pb + c*2304;
                const float pf = tw[0]*fc[toff[0]] + tw[1]*fc[toff[1]]
                               + tw[2]*fc[toff[2]] + tw[3]*fc[toff[3]];
                const float* vc = vb + c*48;
                const float vf = vw[0]*vc[voff[0]] + vw[1]*vc[voff[1]];
                const float r = pf*vf;
                if (c < 8) sigma += r;
                else if (active) gF[s*72 + i*24 + c - 8] = gelu_f(r);
            }
        }
    }

    LDS_FENCE();   // features visible to whole wave; nothing hoists above

    // ======== Phase 2: load weight COLUMNS into registers (lane = hidden j) ========
    float wm[72];
    #pragma unroll
    for (int k=0;k<72;k++) wm[k] = g_wmat[k*64+lane];       // coalesced
    float w1c[64];
    #pragma unroll
    for (int k=0;k<64;k++) w1c[k] = g_w1[k*64+lane];        // coalesced
    const float w20 = g_w2[lane*3+0];
    const float w21 = g_w2[lane*3+1];
    const float w22 = g_w2[lane*3+2];
    const float bm  = g_bmat[lane];
    const float b2l = (lane<3) ? g_b2[lane] : 0.0f;

    // fold the 27 positional-encoding rows of w1 into one per-ray scalar pe_j
    float pe = g_b1[lane];
    {
        const float inv_n = rsqrtf(dx*dx+dy*dy+dz*dz);
        const float vd0=dx*inv_n, vd1=dy*inv_n, vd2=dz*inv_n;
        pe += vd0*g_w1[64*64+lane] + vd1*g_w1[65*64+lane] + vd2*g_w1[66*64+lane];
        #pragma unroll
        for (int fq=0; fq<4; fq++){
            const float fs = (float)(1<<fq);
            pe += sinf(vd0*fs)*g_w1[(67+fq*3+0)*64+lane];
            pe += sinf(vd1*fs)*g_w1[(67+fq*3+1)*64+lane];
            pe += sinf(vd2*fs)*g_w1[(67+fq*3+2)*64+lane];
            pe += cosf(vd0*fs)*g_w1[(79+fq*3+0)*64+lane];
            pe += cosf(vd1*fs)*g_w1[(79+fq*3+1)*64+lane];
            pe += cosf(vd2*fs)*g_w1[(79+fq*3+2)*64+lane];
        }
    }

    MEM_FENCE();

    // ======== Phase 3: MLP, one sample per iteration, lane j owns hidden unit j ========
    #pragma unroll 1
    for (int sp=0; sp<NSMP; sp++){
        const float4* fr = (const float4*)(gF + sp*72);     // wave-uniform -> broadcast
        float acc0=bm, acc1=0.0f, acc2=0.0f, acc3=0.0f;
        #pragma unroll
        for (int g4=0; g4<18; g4++){
            const float4 gv = fr[g4];
            const int k = g4*4;
            const float d = gv.x*wm[k] + gv.y*wm[k+1] + gv.z*wm[k+2] + gv.w*wm[k+3];
            if      ((g4&3)==0) acc0 += d;
            else if ((g4&3)==1) acc1 += d;
            else if ((g4&3)==2) acc2 += d;
            else                acc3 += d;
        }
        const float h = gelu_f((acc0+acc1)+(acc2+acc3));

        LDS_FENCE();            // prior iteration's gH reads fully drained
        gH[lane] = h;
        LDS_FENCE();            // exchange visible to whole wave

        const float4* hr = (const float4*)gH;               // wave-uniform -> broadcast
        float bc0=pe, bc1=0.0f, bc2=0.0f, bc3=0.0f;
        #pragma unroll
        for (int g4=0; g4<16; g4++){
            const float4 hv = hr[g4];
            const int k = g4*4;
            const float d = hv.x*w1c[k] + hv.y*w1c[k+1] + hv.z*w1c[k+2] + hv.w*w1c[k+3];
            if      ((g4&3)==0) bc0 += d;
            else if ((g4&3)==1) bc1 += d;
            else if ((g4&3)==2) bc2 += d;
            else                bc3 += d;
        }
        const float g2 = gelu_f((bc0+bc1)+(bc2+bc3));

        float r0 = g2*w20, r1 = g2*w21, r2 = g2*w22;
        #pragma unroll
        for (int off=32; off; off>>=1){
            r0 += __shfl_xor(r0, off, 64);
            r1 += __shfl_xor(r1, off, 64);
            r2 += __shfl_xor(r2, off, 64);
        }
        if (lane < 3){
            const float rv = (lane==0)? r0 : (lane==1)? r1 : r2;
            gRGB[sp*4+lane] = 1.0f/(1.0f+expf(-(rv+b2l)));
        }
    }

    LDS_FENCE();

    // ======== Phase 4: volume integration (lane = sample again) ========
    const float sg    = fmaxf(sigma, 0.0f);
    const float alpha = active ? (1.0f - expf(-sg*0.03125f)) : 0.0f;
    float v = active ? (1.0f - alpha + 1e-10f) : 1.0f;
    #pragma unroll
    for (int off=1; off<64; off<<=1){
        const float up = __shfl_up(v, off, 64);
        if (lane >= off) v *= up;
    }
    float T = __shfl_up(v, 1, 64);
    if (lane==0) T = 1.0f;
    const float w = alpha*T;                 // inactive lanes: alpha=0 -> w=0

    if (active) out[(size_t)NR*4 + (size_t)ray*NSMP + s] = w;

    const float4 rgbv = *(const float4*)(gRGB + sc*4);
    float A0=w*rgbv.x, A1=w*rgbv.y, A2=w*rgbv.z, AD=w*mid;
    #pragma unroll
    for (int off=32; off>0; off>>=1){
        A0 += __shfl_down(A0, off, 64);
        A1 += __shfl_down(A1, off, 64);
        A2 += __shfl_down(A2, off, 64);
        AD += __shfl_down(AD, off, 64);
    }
    if (lane==0){
        out[(size_t)ray*3+0]=A0;
        out[(size_t)ray*3+1]=A1;
        out[(size_t)ray*3+2]=A2;
        out[(size_t)NR*3 + (size_t)ray]=AD;
    }
}

__global__ void transpose_mats(const float* __restrict__ in, float* __restrict__ out, int total){
    const int idx = blockIdx.x*blockDim.x+threadIdx.x;
    if (idx < total){
        const int pix = idx % 2304;
        const int c   = (idx / 2304) & 31;
        const int ib  = idx / (2304*32);
        out[((size_t)ib*2304+pix)*32 + c] = in[idx];
    }
}

__global__ void transpose_vecs(const float* __restrict__ in, float* __restrict__ out, int total){
    const int idx = blockIdx.x*blockDim.x+threadIdx.x;
    if (idx < total){
        const int r  = idx % 48;
        const int c  = (idx / 48) & 31;
        const int ib = idx / (48*32);
        out[((size_t)ib*48+r)*32 + c] = in[idx];
    }
}

extern "C" void kernel_launch(void* const* d_in, const int* in_sizes, int n_in,
                              void* d_out, int out_size, void* d_ws, size_t ws_size,
                              hipStream_t stream) {
    const float* rays_o  = (const float*)d_in[0];
    const float* rays_d  = (const float*)d_in[1];
    const float* matrixs = (const float*)d_in[2];
    const float* vectors = (const float*)d_in[3];
    const float* w_mat   = (const float*)d_in[4];
    const float* b_mat   = (const float*)d_in[5];
    const float* w1      = (const float*)d_in[6];
    const float* b1      = (const float*)d_in[7];
    const float* w2      = (const float*)d_in[8];
    const float* b2      = (const float*)d_in[9];
    float* out = (float*)d_out;

    const int B = in_sizes[2] / (3*32*48*48);
    const int R = (in_sizes[0]/3) / B;
    const int NR = B*R;

    const int matsz = 3*B*32*2304;
    const int vecsz = 3*B*32*48;
    const size_t need = ((size_t)matsz + (size_t)vecsz)*sizeof(float);

    const int nblk = (NR + 3)/4;
    if (ws_size >= need){
        float* tm = (float*)d_ws;
        float* tv = tm + matsz;
        transpose_mats<<<(matsz+255)/256, 256, 0, stream>>>(matrixs, tm, matsz);
        transpose_vecs<<<(vecsz+255)/256, 256, 0, stream>>>(vectors, tv, vecsz);
        render_kernel<true><<<nblk, 256, 0, stream>>>(rays_o, rays_d, tm, tv,
            w_mat, b_mat, w1, b1, w2, b2, out, B, R);
    } else {
        render_kernel<false><<<nblk, 256, 0, stream>>>(rays_o, rays_d, matrixs, vectors,
            w_mat, b_mat, w1, b1, w2, b2, out, B, R);
    }
}

// Round 4
// 1080.075 us; speedup vs baseline: 94.9808x; 2.2206x over previous
//
#include <hip/hip_runtime.h>
#include <math.h>

#define NSMP 48
#define FSTR 104   // feat row stride in f16 (96 K-padded + 8 pad for banks; 208B, 16B-aligned)
#define HSTR 72    // hid row stride in f16 (64 + 8 pad; 144B, 16B-aligned)
#define WAVES 3

typedef _Float16 f16;
typedef _Float16 half8 __attribute__((ext_vector_type(8)));
typedef _Float16 half4 __attribute__((ext_vector_type(4)));
typedef float    f32x4 __attribute__((ext_vector_type(4)));

__device__ __forceinline__ float gelu_f(float x){
    return 0.5f*x*(1.0f+erff(x*0.70710678118654752f));
}
// wave-synchronous LDS fence (per-wave LDS regions; no __syncthreads anywhere)
#define LDS_FENCE() asm volatile("s_waitcnt lgkmcnt(0)" ::: "memory")

template<bool TR>
__global__ __launch_bounds__(WAVES*64)
void render_kernel(const float* __restrict__ rays_o,
                   const float* __restrict__ rays_d,
                   const float* __restrict__ mats,
                   const float* __restrict__ vecs,
                   const f16*   __restrict__ wT,     // [64][96] f16: wT[n][k] = w_mat[k][n], zero-padded k>=72
                   const float* __restrict__ g_bmat,
                   const f16*   __restrict__ w1T,    // [64][64] f16: w1T[n][k] = w1[k][n] (k<64 rows only)
                   const float* __restrict__ g_b1,
                   const float* __restrict__ g_w1,   // original f32 w1 (for PE rows 64..90)
                   const float* __restrict__ g_w2,
                   const float* __restrict__ g_b2,
                   float* __restrict__ out, int B, int R)
{
    __shared__ f16 s_feat[WAVES][NSMP*FSTR];  // 29952 B
    __shared__ f16 s_hid [WAVES][NSMP*HSTR];  // 20736 B

    const int tid  = threadIdx.x;
    const int wv   = tid >> 6;
    const int lane = tid & 63;
    const int NR   = B*R;
    const int ray  = blockIdx.x*WAVES + wv;
    if (ray >= NR) return;                    // wave-uniform exit
    const int b = ray / R;

    f16* gF = s_feat[wv];
    f16* gH = s_hid[wv];

    const float ox=rays_o[ray*3+0], oy=rays_o[ray*3+1], oz=rays_o[ray*3+2];
    const float dx=rays_d[ray*3+0], dy=rays_d[ray*3+1], dz=rays_d[ray*3+2];

    // ================= Phase 1: gather (lane = sample) =================
    const int  s      = lane;
    const bool active = (s < NSMP);
    const int  sc     = active ? s : (NSMP-1);
    const float mid   = ((float)s  + 0.5f) * 0.03125f;
    const float midc  = ((float)sc + 0.5f) * 0.03125f;

    const float x0c = 1.25f*(ox + dx*midc);
    const float x1c = 1.25f*(oy + dy*midc);
    const float x2c = 1.25f*(oz + dz*midc);

    float sigma = 0.0f;

    #pragma unroll
    for (int i=0;i<3;i++){
        // MAT_MODE = {{0,1},{2,0},{1,2}}, VEC_MODE = {2,1,0}
        const float cx = (i==0)? x0c : (i==1)? x2c : x1c;
        const float cy = (i==0)? x1c : (i==1)? x0c : x2c;
        const float cv = (i==0)? x2c : (i==1)? x1c : x0c;

        const float px = (cx+1.0f)*23.5f;
        const float py = (cy+1.0f)*23.5f;
        const float fx0 = floorf(px), fy0 = floorf(py);
        const float wx = px-fx0, wy = py-fy0;
        const int ix0 = (int)fx0, iy0 = (int)fy0;

        int   toff[4];
        float tw[4];
        #pragma unroll
        for (int t=0;t<4;t++){
            const int xx = ix0 + (t&1);
            const int yy = iy0 + (t>>1);
            const bool inb = (xx>=0)&&(xx<48)&&(yy>=0)&&(yy<48);
            const int xcl = min(max(xx,0),47);
            const int ycl = min(max(yy,0),47);
            toff[t] = ycl*48+xcl;
            const float wxx = (t&1)? wx : 1.0f-wx;
            const float wyy = (t>>1)? wy : 1.0f-wy;
            tw[t] = inb ? wxx*wyy : 0.0f;
        }

        const float pv = (cv+1.0f)*23.5f;
        const float fp0 = floorf(pv);
        const float wvv = pv-fp0;
        const int ip0 = (int)fp0;
        int voff[2]; float vw[2];
        #pragma unroll
        for (int t=0;t<2;t++){
            const int pp = ip0+t;
            const bool inb = (pp>=0)&&(pp<48);
            voff[t] = min(max(pp,0),47);
            vw[t] = inb ? ((t)? wvv : 1.0f-wvv) : 0.0f;
        }

        if (TR){
            const float* pb = mats + ((size_t)(i*B+b))*(2304u*32u);
            const float* vb = vecs + ((size_t)(i*B+b))*(48u*32u);
            const float4* t0 = (const float4*)(pb + toff[0]*32);
            const float4* t1 = (const float4*)(pb + toff[1]*32);
            const float4* t2 = (const float4*)(pb + toff[2]*32);
            const float4* t3 = (const float4*)(pb + toff[3]*32);
            const float4* v0 = (const float4*)(vb + voff[0]*32);
            const float4* v1 = (const float4*)(vb + voff[1]*32);
            #pragma unroll
            for (int c4=0;c4<8;c4++){
                const float4 a0=t0[c4], a1=t1[c4], a2=t2[c4], a3=t3[c4];
                const float4 q0=v0[c4], q1=v1[c4];
                float r0,r1,r2,r3;
                r0 = (tw[0]*a0.x+tw[1]*a1.x+tw[2]*a2.x+tw[3]*a3.x)*(vw[0]*q0.x+vw[1]*q1.x);
                r1 = (tw[0]*a0.y+tw[1]*a1.y+tw[2]*a2.y+tw[3]*a3.y)*(vw[0]*q0.y+vw[1]*q1.y);
                r2 = (tw[0]*a0.z+tw[1]*a1.z+tw[2]*a2.z+tw[3]*a3.z)*(vw[0]*q0.z+vw[1]*q1.z);
                r3 = (tw[0]*a0.w+tw[1]*a1.w+tw[2]*a2.w+tw[3]*a3.w)*(vw[0]*q0.w+vw[1]*q1.w);
                if (c4 < 2){
                    sigma += r0 + r1 + r2 + r3;
                } else if (active){
                    half4 hv = {(f16)gelu_f(r0),(f16)gelu_f(r1),(f16)gelu_f(r2),(f16)gelu_f(r3)};
                    *(half4*)(gF + s*FSTR + i*24 + c4*4 - 8) = hv;
                }
            }
        } else {
            const float* pb = mats + ((size_t)(i*B+b))*(32u*2304u);
            const float* vb = vecs + ((size_t)(i*B+b))*(32u*48u);
            #pragma unroll
            for (int c=0;c<32;c++){
                const float* fc = pb + c*2304;
                const float pf = tw[0]*fc[toff[0]] + tw[1]*fc[toff[1]]
                               + tw[2]*fc[toff[2]] + tw[3]*fc[toff[3]];
                const float* vc = vb + c*48;
                const float vf = vw[0]*vc[voff[0]] + vw[1]*vc[voff[1]];
                const float r = pf*vf;
                if (c < 8) sigma += r;
                else if (active) gF[s*FSTR + i*24 + c - 8] = (f16)gelu_f(r);
            }
        }
    }
    // zero the K-pad region (k = 72..95) so the 3rd K-step multiplies by 0
    if (active){
        half8 z8 = {0,0,0,0,0,0,0,0};
        *(half8*)(gF + s*FSTR + 72) = z8;
        *(half8*)(gF + s*FSTR + 80) = z8;
        *(half8*)(gF + s*FSTR + 88) = z8;
    }

    const int q = lane >> 4;    // quad
    const int cl = lane & 15;   // col index within tile

    // ================= Phase 2: layer-1 GEMM  hid^T(64x48) = wT(64x96) @ feat^T(96x48) =================
    // D layout: col(lane&15)=sample-in-tile, row(q*4+reg)=hidden-in-tile
    f32x4 acc[4][3];
    #pragma unroll
    for (int mt=0;mt<4;mt++){
        const float4 bmv = *(const float4*)(g_bmat + mt*16 + q*4);
        #pragma unroll
        for (int nt=0;nt<3;nt++){
            acc[mt][nt][0]=bmv.x; acc[mt][nt][1]=bmv.y; acc[mt][nt][2]=bmv.z; acc[mt][nt][3]=bmv.w;
        }
    }

    LDS_FENCE();   // feat writes visible to whole wave

    #pragma unroll
    for (int ks=0; ks<3; ks++){
        half8 bf[3];
        #pragma unroll
        for (int nt=0;nt<3;nt++)
            bf[nt] = *(const half8*)(gF + (nt*16+cl)*FSTR + ks*32 + q*8);
        #pragma unroll
        for (int mt=0;mt<4;mt++){
            const half8 af = *(const half8*)(wT + (mt*16+cl)*96 + ks*32 + q*8);
            #pragma unroll
            for (int nt=0;nt<3;nt++)
                acc[mt][nt] = __builtin_amdgcn_mfma_f32_16x16x32_f16(af, bf[nt], acc[mt][nt], 0,0,0);
        }
    }

    // gelu + pack + store hid^T -> LDS [sample][hidden] f16 (one b64 per tile)
    LDS_FENCE();   // B-frag reads of feat drained before we reuse LDS pipe heavily
    #pragma unroll
    for (int mt=0;mt<4;mt++){
        #pragma unroll
        for (int nt=0;nt<3;nt++){
            half4 hv = {(f16)gelu_f(acc[mt][nt][0]), (f16)gelu_f(acc[mt][nt][1]),
                        (f16)gelu_f(acc[mt][nt][2]), (f16)gelu_f(acc[mt][nt][3])};
            *(half4*)(gH + (nt*16+cl)*HSTR + mt*16 + q*4) = hv;
        }
    }

    // ================= Phase 3: PE fold (lane = hidden j) =================
    float pe = g_b1[lane];
    {
        const float inv_n = rsqrtf(dx*dx+dy*dy+dz*dz);
        const float vd0=dx*inv_n, vd1=dy*inv_n, vd2=dz*inv_n;
        pe += vd0*g_w1[64*64+lane] + vd1*g_w1[65*64+lane] + vd2*g_w1[66*64+lane];
        #pragma unroll
        for (int fq=0; fq<4; fq++){
            const float fs = (float)(1<<fq);
            pe += sinf(vd0*fs)*g_w1[(67+fq*3+0)*64+lane];
            pe += sinf(vd1*fs)*g_w1[(67+fq*3+1)*64+lane];
            pe += sinf(vd2*fs)*g_w1[(67+fq*3+2)*64+lane];
            pe += cosf(vd0*fs)*g_w1[(79+fq*3+0)*64+lane];
            pe += cosf(vd1*fs)*g_w1[(79+fq*3+1)*64+lane];
            pe += cosf(vd2*fs)*g_w1[(79+fq*3+2)*64+lane];
        }
    }

    // ================= Phase 4: layer-2 GEMM  h2^T(64x48) = w1T(64x64) @ hid^T(64x48) =================
    f32x4 acc2[4][3];
    #pragma unroll
    for (int mt=0;mt<4;mt++){
        const float p0 = __shfl(pe, mt*16+q*4+0, 64);
        const float p1 = __shfl(pe, mt*16+q*4+1, 64);
        const float p2 = __shfl(pe, mt*16+q*4+2, 64);
        const float p3 = __shfl(pe, mt*16+q*4+3, 64);
        #pragma unroll
        for (int nt=0;nt<3;nt++){
            acc2[mt][nt][0]=p0; acc2[mt][nt][1]=p1; acc2[mt][nt][2]=p2; acc2[mt][nt][3]=p3;
        }
    }

    LDS_FENCE();   // hid writes visible

    #pragma unroll
    for (int ks=0; ks<2; ks++){
        half8 bf[3];
        #pragma unroll
        for (int nt=0;nt<3;nt++)
            bf[nt] = *(const half8*)(gH + (nt*16+cl)*HSTR + ks*32 + q*8);
        #pragma unroll
        for (int mt=0;mt<4;mt++){
            const half8 af = *(const half8*)(w1T + (mt*16+cl)*64 + ks*32 + q*8);
            #pragma unroll
            for (int nt=0;nt<3;nt++)
                acc2[mt][nt] = __builtin_amdgcn_mfma_f32_16x16x32_f16(af, bf[nt], acc2[mt][nt], 0,0,0);
        }
    }

    // ================= Phase 5: layer 3 + sigmoid, straight from C-registers =================
    // lane holds h2[m = mt*16+q*4+reg][sample = nt*16+cl]; per-lane w2 rows: m = mt*16+q*4+r
    float w2a[4][12];
    #pragma unroll
    for (int mt=0;mt<4;mt++){
        const float4* wp = (const float4*)(g_w2 + (size_t)(mt*16+q*4)*3);
        const float4 wa = wp[0], wb = wp[1], wc = wp[2];
        w2a[mt][0]=wa.x; w2a[mt][1]=wa.y; w2a[mt][2]=wa.z;  w2a[mt][3]=wa.w;
        w2a[mt][4]=wb.x; w2a[mt][5]=wb.y; w2a[mt][6]=wb.z;  w2a[mt][7]=wb.w;
        w2a[mt][8]=wc.x; w2a[mt][9]=wc.y; w2a[mt][10]=wc.z; w2a[mt][11]=wc.w;
    }
    const float b20=g_b2[0], b21=g_b2[1], b22=g_b2[2];

    float rgb0=0.0f, rgb1=0.0f, rgb2=0.0f;
    #pragma unroll
    for (int nt=0;nt<3;nt++){
        float r0=0.0f, r1=0.0f, r2=0.0f;
        #pragma unroll
        for (int mt=0;mt<4;mt++){
            #pragma unroll
            for (int r=0;r<4;r++){
                const float g = gelu_f(acc2[mt][nt][r]);
                r0 += g*w2a[mt][r*3+0];
                r1 += g*w2a[mt][r*3+1];
                r2 += g*w2a[mt][r*3+2];
            }
        }
        r0 += __shfl_xor(r0, 16, 64);  r0 += __shfl_xor(r0, 32, 64);
        r1 += __shfl_xor(r1, 16, 64);  r1 += __shfl_xor(r1, 32, 64);
        r2 += __shfl_xor(r2, 16, 64);  r2 += __shfl_xor(r2, 32, 64);
        if (q == nt){   // lane L's own sample is s = L = (L>>4)*16 + (L&15)
            rgb0 = 1.0f/(1.0f+expf(-(r0+b20)));
            rgb1 = 1.0f/(1.0f+expf(-(r1+b21)));
            rgb2 = 1.0f/(1.0f+expf(-(r2+b22)));
        }
    }

    // ================= Phase 6: volume integration (lane = sample) =================
    const float sg    = fmaxf(sigma, 0.0f);
    const float alpha = active ? (1.0f - expf(-sg*0.03125f)) : 0.0f;
    float v = active ? (1.0f - alpha + 1e-10f) : 1.0f;
    #pragma unroll
    for (int off=1; off<64; off<<=1){
        const float up = __shfl_up(v, off, 64);
        if (lane >= off) v *= up;
    }
    float T = __shfl_up(v, 1, 64);
    if (lane==0) T = 1.0f;
    const float w = alpha*T;

    if (active) out[(size_t)NR*4 + (size_t)ray*NSMP + s] = w;

    float A0=w*rgb0, A1=w*rgb1, A2=w*rgb2, AD=w*mid;
    #pragma unroll
    for (int off=32; off>0; off>>=1){
        A0 += __shfl_down(A0, off, 64);
        A1 += __shfl_down(A1, off, 64);
        A2 += __shfl_down(A2, off, 64);
        AD += __shfl_down(AD, off, 64);
    }
    if (lane==0){
        out[(size_t)ray*3+0]=A0;
        out[(size_t)ray*3+1]=A1;
        out[(size_t)ray*3+2]=A2;
        out[(size_t)NR*3 + (size_t)ray]=AD;
    }
}

__global__ void transpose_mats(const float* __restrict__ in, float* __restrict__ out, int total){
    const int idx = blockIdx.x*blockDim.x+threadIdx.x;
    if (idx < total){
        const int pix = idx % 2304;
        const int c   = (idx / 2304) & 31;
        const int ib  = idx / (2304*32);
        out[((size_t)ib*2304+pix)*32 + c] = in[idx];
    }
}

__global__ void transpose_vecs(const float* __restrict__ in, float* __restrict__ out, int total){
    const int idx = blockIdx.x*blockDim.x+threadIdx.x;
    if (idx < total){
        const int r  = idx % 48;
        const int c  = (idx / 48) & 31;
        const int ib = idx / (48*32);
        out[((size_t)ib*48+r)*32 + c] = in[idx];
    }
}

// wT[n][k] (64x96, f16, zero-pad k>=72) and w1T[n][k] (64x64, f16)
__global__ void prep_weights(const float* __restrict__ w_mat, const float* __restrict__ w1,
                             f16* __restrict__ wT, f16* __restrict__ w1T){
    const int idx = blockIdx.x*blockDim.x + threadIdx.x;
    if (idx < 64*96){
        const int n = idx / 96, k = idx % 96;
        wT[idx] = (k < 72) ? (f16)w_mat[k*64+n] : (f16)0.0f;
    } else if (idx < 64*96 + 64*64){
        const int i2 = idx - 64*96;
        const int n = i2 / 64, k = i2 % 64;
        w1T[i2] = (f16)w1[k*64+n];
    }
}

extern "C" void kernel_launch(void* const* d_in, const int* in_sizes, int n_in,
                              void* d_out, int out_size, void* d_ws, size_t ws_size,
                              hipStream_t stream) {
    const float* rays_o  = (const float*)d_in[0];
    const float* rays_d  = (const float*)d_in[1];
    const float* matrixs = (const float*)d_in[2];
    const float* vectors = (const float*)d_in[3];
    const float* w_mat   = (const float*)d_in[4];
    const float* b_mat   = (const float*)d_in[5];
    const float* w1      = (const float*)d_in[6];
    const float* b1      = (const float*)d_in[7];
    const float* w2      = (const float*)d_in[8];
    const float* b2      = (const float*)d_in[9];
    float* out = (float*)d_out;

    const int B = in_sizes[2] / (3*32*48*48);
    const int R = (in_sizes[0]/3) / B;
    const int NR = B*R;

    const int matsz = 3*B*32*2304;
    const int vecsz = 3*B*32*48;
    const size_t need_full = ((size_t)matsz + (size_t)vecsz)*sizeof(float) + (size_t)(64*96+64*64)*sizeof(f16);
    const size_t need_w    = (size_t)(64*96+64*64)*sizeof(f16);

    const int nblk = (NR + WAVES-1)/WAVES;
    const int nthr = WAVES*64;

    if (ws_size >= need_full){
        float* tm = (float*)d_ws;
        float* tv = tm + matsz;
        f16* wT  = (f16*)(tv + vecsz);
        f16* w1T = wT + 64*96;
        transpose_mats<<<(matsz+255)/256, 256, 0, stream>>>(matrixs, tm, matsz);
        transpose_vecs<<<(vecsz+255)/256, 256, 0, stream>>>(vectors, tv, vecsz);
        prep_weights<<<(64*96+64*64+255)/256, 256, 0, stream>>>(w_mat, w1, wT, w1T);
        render_kernel<true><<<nblk, nthr, 0, stream>>>(rays_o, rays_d, tm, tv,
            wT, b_mat, w1T, b1, w1, w2, b2, out, B, R);
    } else if (ws_size >= need_w){
        f16* wT  = (f16*)d_ws;
        f16* w1T = wT + 64*96;
        prep_weights<<<(64*96+64*64+255)/256, 256, 0, stream>>>(w_mat, w1, wT, w1T);
        render_kernel<false><<<nblk, nthr, 0, stream>>>(rays_o, rays_d, matrixs, vectors,
            wT, b_mat, w1T, b1, w1, w2, b2, out, B, R);
    }
}

// Round 5
// 684.700 us; speedup vs baseline: 149.8269x; 1.5774x over previous
//
#include <hip/hip_runtime.h>
#include <math.h>

#define NSMP 48
#define FSTR 104   // feat row stride in f16 (96 K-padded + 8; 208B, 16B-aligned)
#define HSTR 72    // hid row stride in f16 (64 + 8 pad; 144B, 16B-aligned)
#define WAVES 3

typedef _Float16 f16;
typedef _Float16 half8 __attribute__((ext_vector_type(8)));
typedef _Float16 half4 __attribute__((ext_vector_type(4)));
typedef float    f32x4 __attribute__((ext_vector_type(4)));

// fast exact-erf gelu: A&S 7.1.26 minimax (|eps| <= 1.5e-7), branchless
__device__ __forceinline__ float gelu_f(float x){
    const float a = fabsf(x) * 0.70710678118654752f;      // |x|/sqrt(2)
    const float t = __builtin_amdgcn_rcpf(__builtin_fmaf(0.3275911f, a, 1.0f));
    float p = __builtin_fmaf(1.061405429f, t, -1.453152027f);
    p = __builtin_fmaf(p, t, 1.421413741f);
    p = __builtin_fmaf(p, t, -0.284496736f);
    p = __builtin_fmaf(p, t, 0.254829592f);
    p = p * t;
    const float e   = __expf(-a*a);
    const float erf = __builtin_fmaf(-p, e, 1.0f);        // erf(|x|/sqrt2)
    const float se  = (x < 0.0f) ? -erf : erf;
    return 0.5f*x*(1.0f+se);
}
__device__ __forceinline__ float sigmoid_f(float x){
    return __builtin_amdgcn_rcpf(1.0f + __expf(-x));
}
// wave-synchronous LDS fence (per-wave LDS regions; no __syncthreads anywhere)
#define LDS_FENCE() asm volatile("s_waitcnt lgkmcnt(0)" ::: "memory")

template<bool TR>
__global__ __launch_bounds__(WAVES*64, 3)
void render_kernel(const float* __restrict__ rays_o,
                   const float* __restrict__ rays_d,
                   const float* __restrict__ mats,
                   const float* __restrict__ vecs,
                   const f16*   __restrict__ wT,     // [64][96] f16: wT[n][k] = w_mat[k][n], 0-pad k>=72
                   const float* __restrict__ g_bmat,
                   const f16*   __restrict__ w1T,    // [64][64] f16: w1T[n][k] = w1[k][n]
                   const float* __restrict__ g_b1,
                   const float* __restrict__ g_w1,   // original f32 w1 (PE rows 64..90)
                   const float* __restrict__ g_w2,
                   const float* __restrict__ g_b2,
                   float* __restrict__ out, int B, int R)
{
    // single per-wave buffer: feat (48*104 f16) phase 1-2, then hid overlays it (48*72 f16)
    __shared__ f16 s_buf[WAVES][NSMP*FSTR];   // 29952 B total

    const int tid  = threadIdx.x;
    const int wv   = tid >> 6;
    const int lane = tid & 63;
    const int NR   = B*R;
    const int ray  = blockIdx.x*WAVES + wv;
    if (ray >= NR) return;                    // wave-uniform exit
    const int b = ray / R;

    f16* gF = s_buf[wv];
    f16* gH = s_buf[wv];                      // overlay (HSTR rows fit inside FSTR region)

    const float ox=rays_o[ray*3+0], oy=rays_o[ray*3+1], oz=rays_o[ray*3+2];
    const float dx=rays_d[ray*3+0], dy=rays_d[ray*3+1], dz=rays_d[ray*3+2];

    // ================= Phase 1: gather (lane = sample) =================
    const int  s      = lane;
    const bool active = (s < NSMP);
    const int  sc     = active ? s : (NSMP-1);
    const float mid   = ((float)s  + 0.5f) * 0.03125f;
    const float midc  = ((float)sc + 0.5f) * 0.03125f;

    const float x0c = 1.25f*(ox + dx*midc);
    const float x1c = 1.25f*(oy + dy*midc);
    const float x2c = 1.25f*(oz + dz*midc);

    float sigma = 0.0f;

    #pragma unroll
    for (int i=0;i<3;i++){
        // MAT_MODE = {{0,1},{2,0},{1,2}}, VEC_MODE = {2,1,0}
        const float cx = (i==0)? x0c : (i==1)? x2c : x1c;
        const float cy = (i==0)? x1c : (i==1)? x0c : x2c;
        const float cv = (i==0)? x2c : (i==1)? x1c : x0c;

        const float px = (cx+1.0f)*23.5f;
        const float py = (cy+1.0f)*23.5f;
        const float fx0 = floorf(px), fy0 = floorf(py);
        const float wx = px-fx0, wy = py-fy0;
        const int ix0 = (int)fx0, iy0 = (int)fy0;

        int   toff[4];
        float tw[4];
        #pragma unroll
        for (int t=0;t<4;t++){
            const int xx = ix0 + (t&1);
            const int yy = iy0 + (t>>1);
            const bool inb = (xx>=0)&&(xx<48)&&(yy>=0)&&(yy<48);
            const int xcl = min(max(xx,0),47);
            const int ycl = min(max(yy,0),47);
            toff[t] = ycl*48+xcl;
            const float wxx = (t&1)? wx : 1.0f-wx;
            const float wyy = (t>>1)? wy : 1.0f-wy;
            tw[t] = inb ? wxx*wyy : 0.0f;
        }

        const float pv = (cv+1.0f)*23.5f;
        const float fp0 = floorf(pv);
        const float wvv = pv-fp0;
        const int ip0 = (int)fp0;
        int voff[2]; float vw[2];
        #pragma unroll
        for (int t=0;t<2;t++){
            const int pp = ip0+t;
            const bool inb = (pp>=0)&&(pp<48);
            voff[t] = min(max(pp,0),47);
            vw[t] = inb ? ((t)? wvv : 1.0f-wvv) : 0.0f;
        }

        if (TR){
            const float* pb = mats + ((size_t)(i*B+b))*(2304u*32u);
            const float* vb = vecs + ((size_t)(i*B+b))*(48u*32u);
            const float4* t0 = (const float4*)(pb + toff[0]*32);
            const float4* t1 = (const float4*)(pb + toff[1]*32);
            const float4* t2 = (const float4*)(pb + toff[2]*32);
            const float4* t3 = (const float4*)(pb + toff[3]*32);
            const float4* v0 = (const float4*)(vb + voff[0]*32);
            const float4* v1 = (const float4*)(vb + voff[1]*32);
            #pragma unroll
            for (int c4=0;c4<8;c4++){
                const float4 a0=t0[c4], a1=t1[c4], a2=t2[c4], a3=t3[c4];
                const float4 q0=v0[c4], q1=v1[c4];
                float r0,r1,r2,r3;
                r0 = (tw[0]*a0.x+tw[1]*a1.x+tw[2]*a2.x+tw[3]*a3.x)*(vw[0]*q0.x+vw[1]*q1.x);
                r1 = (tw[0]*a0.y+tw[1]*a1.y+tw[2]*a2.y+tw[3]*a3.y)*(vw[0]*q0.y+vw[1]*q1.y);
                r2 = (tw[0]*a0.z+tw[1]*a1.z+tw[2]*a2.z+tw[3]*a3.z)*(vw[0]*q0.z+vw[1]*q1.z);
                r3 = (tw[0]*a0.w+tw[1]*a1.w+tw[2]*a2.w+tw[3]*a3.w)*(vw[0]*q0.w+vw[1]*q1.w);
                if (c4 < 2){
                    sigma += r0 + r1 + r2 + r3;
                } else if (active){
                    half4 hv = {(f16)gelu_f(r0),(f16)gelu_f(r1),(f16)gelu_f(r2),(f16)gelu_f(r3)};
                    *(half4*)(gF + s*FSTR + i*24 + c4*4 - 8) = hv;
                }
            }
        } else {
            const float* pb = mats + ((size_t)(i*B+b))*(32u*2304u);
            const float* vb = vecs + ((size_t)(i*B+b))*(32u*48u);
            #pragma unroll
            for (int c=0;c<32;c++){
                const float* fc = pb + c*2304;
                const float pf = tw[0]*fc[toff[0]] + tw[1]*fc[toff[1]]
                               + tw[2]*fc[toff[2]] + tw[3]*fc[toff[3]];
                const float* vc = vb + c*48;
                const float vf = vw[0]*vc[voff[0]] + vw[1]*vc[voff[1]];
                const float r = pf*vf;
                if (c < 8) sigma += r;
                else if (active) gF[s*FSTR + i*24 + c - 8] = (f16)gelu_f(r);
            }
        }
    }
    // zero the K-pad region (k = 72..95)
    if (active){
        half8 z8 = {0,0,0,0,0,0,0,0};
        *(half8*)(gF + s*FSTR + 72) = z8;
        *(half8*)(gF + s*FSTR + 80) = z8;
        *(half8*)(gF + s*FSTR + 88) = z8;
    }

    const int q  = lane >> 4;   // quad
    const int cl = lane & 15;   // col index within tile

    // ======== Phase 2: layer-1 GEMM  hid^T(64x48) = wT(64x96) @ feat^T(96x48) ========
    f32x4 acc[4][3];
    #pragma unroll
    for (int mt=0;mt<4;mt++){
        const float4 bmv = *(const float4*)(g_bmat + mt*16 + q*4);
        #pragma unroll
        for (int nt=0;nt<3;nt++){
            acc[mt][nt][0]=bmv.x; acc[mt][nt][1]=bmv.y; acc[mt][nt][2]=bmv.z; acc[mt][nt][3]=bmv.w;
        }
    }

    LDS_FENCE();   // feat writes visible to whole wave

    #pragma unroll
    for (int ks=0; ks<3; ks++){
        half8 bf[3];
        #pragma unroll
        for (int nt=0;nt<3;nt++)
            bf[nt] = *(const half8*)(gF + (nt*16+cl)*FSTR + ks*32 + q*8);
        #pragma unroll
        for (int mt=0;mt<4;mt++){
            const half8 af = *(const half8*)(wT + (mt*16+cl)*96 + ks*32 + q*8);
            #pragma unroll
            for (int nt=0;nt<3;nt++)
                acc[mt][nt] = __builtin_amdgcn_mfma_f32_16x16x32_f16(af, bf[nt], acc[mt][nt], 0,0,0);
        }
    }

    // gelu + pack + store hid^T into the SAME LDS region (feat fully consumed)
    LDS_FENCE();   // all feat reads drained before overwrite
    #pragma unroll
    for (int mt=0;mt<4;mt++){
        #pragma unroll
        for (int nt=0;nt<3;nt++){
            half4 hv = {(f16)gelu_f(acc[mt][nt][0]), (f16)gelu_f(acc[mt][nt][1]),
                        (f16)gelu_f(acc[mt][nt][2]), (f16)gelu_f(acc[mt][nt][3])};
            *(half4*)(gH + (nt*16+cl)*HSTR + mt*16 + q*4) = hv;
        }
    }

    // ================= Phase 3: PE fold (lane = hidden j) =================
    float pe = g_b1[lane];
    {
        const float inv_n = rsqrtf(dx*dx+dy*dy+dz*dz);
        const float vd0=dx*inv_n, vd1=dy*inv_n, vd2=dz*inv_n;
        pe += vd0*g_w1[64*64+lane] + vd1*g_w1[65*64+lane] + vd2*g_w1[66*64+lane];
        #pragma unroll
        for (int fq=0; fq<4; fq++){
            const float fs = (float)(1<<fq);
            pe += __sinf(vd0*fs)*g_w1[(67+fq*3+0)*64+lane];
            pe += __sinf(vd1*fs)*g_w1[(67+fq*3+1)*64+lane];
            pe += __sinf(vd2*fs)*g_w1[(67+fq*3+2)*64+lane];
            pe += __cosf(vd0*fs)*g_w1[(79+fq*3+0)*64+lane];
            pe += __cosf(vd1*fs)*g_w1[(79+fq*3+1)*64+lane];
            pe += __cosf(vd2*fs)*g_w1[(79+fq*3+2)*64+lane];
        }
    }

    // ======== Phase 4: layer-2 GEMM  h2^T(64x48) = w1T(64x64) @ hid^T(64x48) ========
    f32x4 acc2[4][3];
    #pragma unroll
    for (int mt=0;mt<4;mt++){
        const float p0 = __shfl(pe, mt*16+q*4+0, 64);
        const float p1 = __shfl(pe, mt*16+q*4+1, 64);
        const float p2 = __shfl(pe, mt*16+q*4+2, 64);
        const float p3 = __shfl(pe, mt*16+q*4+3, 64);
        #pragma unroll
        for (int nt=0;nt<3;nt++){
            acc2[mt][nt][0]=p0; acc2[mt][nt][1]=p1; acc2[mt][nt][2]=p2; acc2[mt][nt][3]=p3;
        }
    }

    LDS_FENCE();   // hid writes visible

    #pragma unroll
    for (int ks=0; ks<2; ks++){
        half8 bf[3];
        #pragma unroll
        for (int nt=0;nt<3;nt++)
            bf[nt] = *(const half8*)(gH + (nt*16+cl)*HSTR + ks*32 + q*8);
        #pragma unroll
        for (int mt=0;mt<4;mt++){
            const half8 af = *(const half8*)(w1T + (mt*16+cl)*64 + ks*32 + q*8);
            #pragma unroll
            for (int nt=0;nt<3;nt++)
                acc2[mt][nt] = __builtin_amdgcn_mfma_f32_16x16x32_f16(af, bf[nt], acc2[mt][nt], 0,0,0);
        }
    }

    // ======== Phase 5: layer 3 + sigmoid, straight from C-registers ========
    const float b20=g_b2[0], b21=g_b2[1], b22=g_b2[2];
    float rgb0=0.0f, rgb1=0.0f, rgb2=0.0f;
    #pragma unroll
    for (int nt=0;nt<3;nt++){
        float r0=0.0f, r1=0.0f, r2=0.0f;
        #pragma unroll
        for (int mt=0;mt<4;mt++){
            const float4* wp = (const float4*)(g_w2 + (size_t)(mt*16+q*4)*3);
            const float4 wa = wp[0], wb = wp[1], wc = wp[2];
            const float g0 = gelu_f(acc2[mt][nt][0]);
            const float g1 = gelu_f(acc2[mt][nt][1]);
            const float g2 = gelu_f(acc2[mt][nt][2]);
            const float g3 = gelu_f(acc2[mt][nt][3]);
            r0 += g0*wa.x + g1*wa.w + g2*wb.z + g3*wc.y;
            r1 += g0*wa.y + g1*wb.x + g2*wb.w + g3*wc.z;
            r2 += g0*wa.z + g1*wb.y + g2*wc.x + g3*wc.w;
        }
        r0 += __shfl_xor(r0, 16, 64);  r0 += __shfl_xor(r0, 32, 64);
        r1 += __shfl_xor(r1, 16, 64);  r1 += __shfl_xor(r1, 32, 64);
        r2 += __shfl_xor(r2, 16, 64);  r2 += __shfl_xor(r2, 32, 64);
        if (q == nt){
            rgb0 = sigmoid_f(r0+b20);
            rgb1 = sigmoid_f(r1+b21);
            rgb2 = sigmoid_f(r2+b22);
        }
    }

    // ======== Phase 6: volume integration (lane = sample) ========
    const float sg    = fmaxf(sigma, 0.0f);
    const float alpha = active ? (1.0f - __expf(-sg*0.03125f)) : 0.0f;
    float v = active ? (1.0f - alpha + 1e-10f) : 1.0f;
    #pragma unroll
    for (int off=1; off<64; off<<=1){
        const float up = __shfl_up(v, off, 64);
        if (lane >= off) v *= up;
    }
    float T = __shfl_up(v, 1, 64);
    if (lane==0) T = 1.0f;
    const float w = alpha*T;

    if (active) out[(size_t)NR*4 + (size_t)ray*NSMP + s] = w;

    float A0=w*rgb0, A1=w*rgb1, A2=w*rgb2, AD=w*mid;
    #pragma unroll
    for (int off=32; off>0; off>>=1){
        A0 += __shfl_down(A0, off, 64);
        A1 += __shfl_down(A1, off, 64);
        A2 += __shfl_down(A2, off, 64);
        AD += __shfl_down(AD, off, 64);
    }
    if (lane==0){
        out[(size_t)ray*3+0]=A0;
        out[(size_t)ray*3+1]=A1;
        out[(size_t)ray*3+2]=A2;
        out[(size_t)NR*3 + (size_t)ray]=AD;
    }
}

__global__ void transpose_mats(const float* __restrict__ in, float* __restrict__ out, int total){
    const int idx = blockIdx.x*blockDim.x+threadIdx.x;
    if (idx < total){
        const int pix = idx % 2304;
        const int c   = (idx / 2304) & 31;
        const int ib  = idx / (2304*32);
        out[((size_t)ib*2304+pix)*32 + c] = in[idx];
    }
}

__global__ void transpose_vecs(const float* __restrict__ in, float* __restrict__ out, int total){
    const int idx = blockIdx.x*blockDim.x+threadIdx.x;
    if (idx < total){
        const int r  = idx % 48;
        const int c  = (idx / 48) & 31;
        const int ib = idx / (48*32);
        out[((size_t)ib*48+r)*32 + c] = in[idx];
    }
}

// wT[n][k] (64x96 f16, zero-pad k>=72) and w1T[n][k] (64x64 f16)
__global__ void prep_weights(const float* __restrict__ w_mat, const float* __restrict__ w1,
                             f16* __restrict__ wT, f16* __restrict__ w1T){
    const int idx = blockIdx.x*blockDim.x + threadIdx.x;
    if (idx < 64*96){
        const int n = idx / 96, k = idx % 96;
        wT[idx] = (k < 72) ? (f16)w_mat[k*64+n] : (f16)0.0f;
    } else if (idx < 64*96 + 64*64){
        const int i2 = idx - 64*96;
        const int n = i2 / 64, k = i2 % 64;
        w1T[i2] = (f16)w1[k*64+n];
    }
}

extern "C" void kernel_launch(void* const* d_in, const int* in_sizes, int n_in,
                              void* d_out, int out_size, void* d_ws, size_t ws_size,
                              hipStream_t stream) {
    const float* rays_o  = (const float*)d_in[0];
    const float* rays_d  = (const float*)d_in[1];
    const float* matrixs = (const float*)d_in[2];
    const float* vectors = (const float*)d_in[3];
    const float* w_mat   = (const float*)d_in[4];
    const float* b_mat   = (const float*)d_in[5];
    const float* w1      = (const float*)d_in[6];
    const float* b1      = (const float*)d_in[7];
    const float* w2      = (const float*)d_in[8];
    const float* b2      = (const float*)d_in[9];
    float* out = (float*)d_out;

    const int B = in_sizes[2] / (3*32*48*48);
    const int R = (in_sizes[0]/3) / B;
    const int NR = B*R;

    const int matsz = 3*B*32*2304;
    const int vecsz = 3*B*32*48;
    const size_t need_full = ((size_t)matsz + (size_t)vecsz)*sizeof(float) + (size_t)(64*96+64*64)*sizeof(f16);
    const size_t need_w    = (size_t)(64*96+64*64)*sizeof(f16);

    const int nblk = (NR + WAVES-1)/WAVES;
    const int nthr = WAVES*64;

    if (ws_size >= need_full){
        float* tm = (float*)d_ws;
        float* tv = tm + matsz;
        f16* wT  = (f16*)(tv + vecsz);
        f16* w1T = wT + 64*96;
        transpose_mats<<<(matsz+255)/256, 256, 0, stream>>>(matrixs, tm, matsz);
        transpose_vecs<<<(vecsz+255)/256, 256, 0, stream>>>(vectors, tv, vecsz);
        prep_weights<<<(64*96+64*64+255)/256, 256, 0, stream>>>(w_mat, w1, wT, w1T);
        render_kernel<true><<<nblk, nthr, 0, stream>>>(rays_o, rays_d, tm, tv,
            wT, b_mat, w1T, b1, w1, w2, b2, out, B, R);
    } else if (ws_size >= need_w){
        f16* wT  = (f16*)d_ws;
        f16* w1T = wT + 64*96;
        prep_weights<<<(64*96+64*64+255)/256, 256, 0, stream>>>(w_mat, w1, wT, w1T);
        render_kernel<false><<<nblk, nthr, 0, stream>>>(rays_o, rays_d, matrixs, vectors,
            wT, b_mat, w1T, b1, w1, w2, b2, out, B, R);
    }
}

// Round 6
// 463.156 us; speedup vs baseline: 221.4944x; 1.4783x over previous
//
#include <hip/hip_runtime.h>
#include <math.h>

#define NSMP 48
#define FSTR 104   // feat row stride in f16 (96 K-padded + 8; 208B, 16B-aligned)
#define HSTR 72    // hid row stride in f16 (64 + 8 pad; 144B, 16B-aligned)
#define WAVES 3

typedef _Float16 f16;
typedef _Float16 half8 __attribute__((ext_vector_type(8)));
typedef _Float16 half4 __attribute__((ext_vector_type(4)));
typedef float    f32x4 __attribute__((ext_vector_type(4)));

// fast exact-erf gelu: A&S 7.1.26 minimax (|eps| <= 1.5e-7), branchless
__device__ __forceinline__ float gelu_f(float x){
    const float a = fabsf(x) * 0.70710678118654752f;      // |x|/sqrt(2)
    const float t = __builtin_amdgcn_rcpf(__builtin_fmaf(0.3275911f, a, 1.0f));
    float p = __builtin_fmaf(1.061405429f, t, -1.453152027f);
    p = __builtin_fmaf(p, t, 1.421413741f);
    p = __builtin_fmaf(p, t, -0.284496736f);
    p = __builtin_fmaf(p, t, 0.254829592f);
    p = p * t;
    const float e   = __expf(-a*a);
    const float erf = __builtin_fmaf(-p, e, 1.0f);        // erf(|x|/sqrt2)
    const float se  = (x < 0.0f) ? -erf : erf;
    return 0.5f*x*(1.0f+se);
}
__device__ __forceinline__ float sigmoid_f(float x){
    return __builtin_amdgcn_rcpf(1.0f + __expf(-x));
}
// wave-synchronous LDS fence (per-wave LDS regions; no __syncthreads anywhere)
#define LDS_FENCE() asm volatile("s_waitcnt lgkmcnt(0)" ::: "memory")

template<bool TR>
__global__ __launch_bounds__(WAVES*64, 3)
void render_kernel(const float* __restrict__ rays_o,
                   const float* __restrict__ rays_d,
                   const float* __restrict__ mats,
                   const float* __restrict__ vecs,
                   const f16*   __restrict__ wT,     // [64][96] f16: wT[n][k] = w_mat[k][n], 0-pad k>=72
                   const float* __restrict__ g_bmat,
                   const f16*   __restrict__ w1T,    // [64][64] f16: w1T[n][k] = w1[k][n]
                   const float* __restrict__ g_b1,
                   const float* __restrict__ g_w1,   // original f32 w1 (PE rows 64..90)
                   const float* __restrict__ g_w2,
                   const float* __restrict__ g_b2,
                   float* __restrict__ out, int B, int R)
{
    // single per-wave buffer: feat (48*104 f16) phase 1-2, then hid overlays it (48*72 f16)
    __shared__ f16 s_buf[WAVES][NSMP*FSTR];   // 29952 B total

    const int tid  = threadIdx.x;
    const int wv   = tid >> 6;
    const int lane = tid & 63;
    const int NR   = B*R;
    const int ray  = blockIdx.x*WAVES + wv;
    if (ray >= NR) return;                    // wave-uniform exit
    const int b = ray / R;

    f16* gF = s_buf[wv];
    f16* gH = s_buf[wv];                      // overlay (HSTR rows fit inside FSTR region)

    const float ox=rays_o[ray*3+0], oy=rays_o[ray*3+1], oz=rays_o[ray*3+2];
    const float dx=rays_d[ray*3+0], dy=rays_d[ray*3+1], dz=rays_d[ray*3+2];

    // ================= Phase 1: gather (lane = sample) =================
    const int  s      = lane;
    const bool active = (s < NSMP);
    const int  sc     = active ? s : (NSMP-1);
    const float mid   = ((float)s  + 0.5f) * 0.03125f;
    const float midc  = ((float)sc + 0.5f) * 0.03125f;

    const float x0c = 1.25f*(ox + dx*midc);
    const float x1c = 1.25f*(oy + dy*midc);
    const float x2c = 1.25f*(oz + dz*midc);

    float sigma = 0.0f;

    // one plane at a time: bounds the in-flight global-load set (reg pressure)
    #pragma unroll 1
    for (int i=0;i<3;i++){
        // MAT_MODE = {{0,1},{2,0},{1,2}}, VEC_MODE = {2,1,0}
        const float cx = (i==0)? x0c : (i==1)? x2c : x1c;
        const float cy = (i==0)? x1c : (i==1)? x0c : x2c;
        const float cv = (i==0)? x2c : (i==1)? x1c : x0c;

        const float px = (cx+1.0f)*23.5f;
        const float py = (cy+1.0f)*23.5f;
        const float fx0 = floorf(px), fy0 = floorf(py);
        const float wx = px-fx0, wy = py-fy0;
        const int ix0 = (int)fx0, iy0 = (int)fy0;

        int   toff[4];
        float tw[4];
        #pragma unroll
        for (int t=0;t<4;t++){
            const int xx = ix0 + (t&1);
            const int yy = iy0 + (t>>1);
            const bool inb = (xx>=0)&&(xx<48)&&(yy>=0)&&(yy<48);
            const int xcl = min(max(xx,0),47);
            const int ycl = min(max(yy,0),47);
            toff[t] = ycl*48+xcl;
            const float wxx = (t&1)? wx : 1.0f-wx;
            const float wyy = (t>>1)? wy : 1.0f-wy;
            tw[t] = inb ? wxx*wyy : 0.0f;
        }

        const float pv = (cv+1.0f)*23.5f;
        const float fp0 = floorf(pv);
        const float wvv = pv-fp0;
        const int ip0 = (int)fp0;
        int voff[2]; float vw[2];
        #pragma unroll
        for (int t=0;t<2;t++){
            const int pp = ip0+t;
            const bool inb = (pp>=0)&&(pp<48);
            voff[t] = min(max(pp,0),47);
            vw[t] = inb ? ((t)? wvv : 1.0f-wvv) : 0.0f;
        }

        if (TR){
            const float* pb = mats + ((size_t)(i*B+b))*(2304u*32u);
            const float* vb = vecs + ((size_t)(i*B+b))*(48u*32u);
            const float4* t0 = (const float4*)(pb + toff[0]*32);
            const float4* t1 = (const float4*)(pb + toff[1]*32);
            const float4* t2 = (const float4*)(pb + toff[2]*32);
            const float4* t3 = (const float4*)(pb + toff[3]*32);
            const float4* v0 = (const float4*)(vb + voff[0]*32);
            const float4* v1 = (const float4*)(vb + voff[1]*32);
            // unroll 2: <=12 float4 loads in flight (48 VGPRs), not 32 (128)
            #pragma unroll 2
            for (int c4=0;c4<8;c4++){
                const float4 a0=t0[c4], a1=t1[c4], a2=t2[c4], a3=t3[c4];
                const float4 q0=v0[c4], q1=v1[c4];
                float r0,r1,r2,r3;
                r0 = (tw[0]*a0.x+tw[1]*a1.x+tw[2]*a2.x+tw[3]*a3.x)*(vw[0]*q0.x+vw[1]*q1.x);
                r1 = (tw[0]*a0.y+tw[1]*a1.y+tw[2]*a2.y+tw[3]*a3.y)*(vw[0]*q0.y+vw[1]*q1.y);
                r2 = (tw[0]*a0.z+tw[1]*a1.z+tw[2]*a2.z+tw[3]*a3.z)*(vw[0]*q0.z+vw[1]*q1.z);
                r3 = (tw[0]*a0.w+tw[1]*a1.w+tw[2]*a2.w+tw[3]*a3.w)*(vw[0]*q0.w+vw[1]*q1.w);
                if (c4 < 2){
                    sigma += r0 + r1 + r2 + r3;
                } else if (active){
                    half4 hv = {(f16)gelu_f(r0),(f16)gelu_f(r1),(f16)gelu_f(r2),(f16)gelu_f(r3)};
                    *(half4*)(gF + s*FSTR + i*24 + c4*4 - 8) = hv;
                }
            }
        } else {
            const float* pb = mats + ((size_t)(i*B+b))*(32u*2304u);
            const float* vb = vecs + ((size_t)(i*B+b))*(32u*48u);
            #pragma unroll 2
            for (int c=0;c<32;c++){
                const float* fc = pb + c*2304;
                const float pf = tw[0]*fc[toff[0]] + tw[1]*fc[toff[1]]
                               + tw[2]*fc[toff[2]] + tw[3]*fc[toff[3]];
                const float* vc = vb + c*48;
                const float vf = vw[0]*vc[voff[0]] + vw[1]*vc[voff[1]];
                const float r = pf*vf;
                if (c < 8) sigma += r;
                else if (active) gF[s*FSTR + i*24 + c - 8] = (f16)gelu_f(r);
            }
        }
    }
    // zero the K-pad region (k = 72..95)
    if (active){
        half8 z8 = {0,0,0,0,0,0,0,0};
        *(half8*)(gF + s*FSTR + 72) = z8;
        *(half8*)(gF + s*FSTR + 80) = z8;
        *(half8*)(gF + s*FSTR + 88) = z8;
    }

    const int q  = lane >> 4;   // quad
    const int cl = lane & 15;   // col index within tile

    // ======== Phase 2: layer-1 GEMM  hid^T(64x48) = wT(64x96) @ feat^T(96x48) ========
    f32x4 acc[4][3];
    #pragma unroll
    for (int mt=0;mt<4;mt++){
        const float4 bmv = *(const float4*)(g_bmat + mt*16 + q*4);
        #pragma unroll
        for (int nt=0;nt<3;nt++){
            acc[mt][nt][0]=bmv.x; acc[mt][nt][1]=bmv.y; acc[mt][nt][2]=bmv.z; acc[mt][nt][3]=bmv.w;
        }
    }

    LDS_FENCE();   // feat writes visible to whole wave

    // unroll 1: one K-step's frags in flight at a time
    #pragma unroll 1
    for (int ks=0; ks<3; ks++){
        half8 bf[3];
        #pragma unroll
        for (int nt=0;nt<3;nt++)
            bf[nt] = *(const half8*)(gF + (nt*16+cl)*FSTR + ks*32 + q*8);
        #pragma unroll
        for (int mt=0;mt<4;mt++){
            const half8 af = *(const half8*)(wT + (mt*16+cl)*96 + ks*32 + q*8);
            #pragma unroll
            for (int nt=0;nt<3;nt++)
                acc[mt][nt] = __builtin_amdgcn_mfma_f32_16x16x32_f16(af, bf[nt], acc[mt][nt], 0,0,0);
        }
    }

    // gelu + pack + store hid^T into the SAME LDS region (feat fully consumed)
    LDS_FENCE();   // all feat reads drained before overwrite
    #pragma unroll
    for (int mt=0;mt<4;mt++){
        #pragma unroll
        for (int nt=0;nt<3;nt++){
            half4 hv = {(f16)gelu_f(acc[mt][nt][0]), (f16)gelu_f(acc[mt][nt][1]),
                        (f16)gelu_f(acc[mt][nt][2]), (f16)gelu_f(acc[mt][nt][3])};
            *(half4*)(gH + (nt*16+cl)*HSTR + mt*16 + q*4) = hv;
        }
    }

    // ================= Phase 3: PE fold (lane = hidden j) =================
    float pe = g_b1[lane];
    {
        const float inv_n = rsqrtf(dx*dx+dy*dy+dz*dz);
        const float vd0=dx*inv_n, vd1=dy*inv_n, vd2=dz*inv_n;
        pe += vd0*g_w1[64*64+lane] + vd1*g_w1[65*64+lane] + vd2*g_w1[66*64+lane];
        #pragma unroll 1
        for (int fq=0; fq<4; fq++){
            const float fs = (float)(1<<fq);
            pe += __sinf(vd0*fs)*g_w1[(67+fq*3+0)*64+lane];
            pe += __sinf(vd1*fs)*g_w1[(67+fq*3+1)*64+lane];
            pe += __sinf(vd2*fs)*g_w1[(67+fq*3+2)*64+lane];
            pe += __cosf(vd0*fs)*g_w1[(79+fq*3+0)*64+lane];
            pe += __cosf(vd1*fs)*g_w1[(79+fq*3+1)*64+lane];
            pe += __cosf(vd2*fs)*g_w1[(79+fq*3+2)*64+lane];
        }
    }

    // ======== Phase 4: layer-2 GEMM  h2^T(64x48) = w1T(64x64) @ hid^T(64x48) ========
    f32x4 acc2[4][3];
    #pragma unroll
    for (int mt=0;mt<4;mt++){
        const float p0 = __shfl(pe, mt*16+q*4+0, 64);
        const float p1 = __shfl(pe, mt*16+q*4+1, 64);
        const float p2 = __shfl(pe, mt*16+q*4+2, 64);
        const float p3 = __shfl(pe, mt*16+q*4+3, 64);
        #pragma unroll
        for (int nt=0;nt<3;nt++){
            acc2[mt][nt][0]=p0; acc2[mt][nt][1]=p1; acc2[mt][nt][2]=p2; acc2[mt][nt][3]=p3;
        }
    }

    LDS_FENCE();   // hid writes visible

    #pragma unroll 1
    for (int ks=0; ks<2; ks++){
        half8 bf[3];
        #pragma unroll
        for (int nt=0;nt<3;nt++)
            bf[nt] = *(const half8*)(gH + (nt*16+cl)*HSTR + ks*32 + q*8);
        #pragma unroll
        for (int mt=0;mt<4;mt++){
            const half8 af = *(const half8*)(w1T + (mt*16+cl)*64 + ks*32 + q*8);
            #pragma unroll
            for (int nt=0;nt<3;nt++)
                acc2[mt][nt] = __builtin_amdgcn_mfma_f32_16x16x32_f16(af, bf[nt], acc2[mt][nt], 0,0,0);
        }
    }

    // ======== Phase 5: layer 3 + sigmoid, straight from C-registers ========
    const float b20=g_b2[0], b21=g_b2[1], b22=g_b2[2];
    float rgb0=0.0f, rgb1=0.0f, rgb2=0.0f;
    #pragma unroll
    for (int nt=0;nt<3;nt++){
        float r0=0.0f, r1=0.0f, r2=0.0f;
        #pragma unroll
        for (int mt=0;mt<4;mt++){
            const float4* wp = (const float4*)(g_w2 + (size_t)(mt*16+q*4)*3);
            const float4 wa = wp[0], wb = wp[1], wc = wp[2];
            const float g0 = gelu_f(acc2[mt][nt][0]);
            const float g1 = gelu_f(acc2[mt][nt][1]);
            const float g2 = gelu_f(acc2[mt][nt][2]);
            const float g3 = gelu_f(acc2[mt][nt][3]);
            r0 += g0*wa.x + g1*wa.w + g2*wb.z + g3*wc.y;
            r1 += g0*wa.y + g1*wb.x + g2*wb.w + g3*wc.z;
            r2 += g0*wa.z + g1*wb.y + g2*wc.x + g3*wc.w;
        }
        r0 += __shfl_xor(r0, 16, 64);  r0 += __shfl_xor(r0, 32, 64);
        r1 += __shfl_xor(r1, 16, 64);  r1 += __shfl_xor(r1, 32, 64);
        r2 += __shfl_xor(r2, 16, 64);  r2 += __shfl_xor(r2, 32, 64);
        if (q == nt){
            rgb0 = sigmoid_f(r0+b20);
            rgb1 = sigmoid_f(r1+b21);
            rgb2 = sigmoid_f(r2+b22);
        }
    }

    // ======== Phase 6: volume integration (lane = sample) ========
    const float sg    = fmaxf(sigma, 0.0f);
    const float alpha = active ? (1.0f - __expf(-sg*0.03125f)) : 0.0f;
    float v = active ? (1.0f - alpha + 1e-10f) : 1.0f;
    #pragma unroll
    for (int off=1; off<64; off<<=1){
        const float up = __shfl_up(v, off, 64);
        if (lane >= off) v *= up;
    }
    float T = __shfl_up(v, 1, 64);
    if (lane==0) T = 1.0f;
    const float w = alpha*T;

    if (active) out[(size_t)NR*4 + (size_t)ray*NSMP + s] = w;

    float A0=w*rgb0, A1=w*rgb1, A2=w*rgb2, AD=w*mid;
    #pragma unroll
    for (int off=32; off>0; off>>=1){
        A0 += __shfl_down(A0, off, 64);
        A1 += __shfl_down(A1, off, 64);
        A2 += __shfl_down(A2, off, 64);
        AD += __shfl_down(AD, off, 64);
    }
    if (lane==0){
        out[(size_t)ray*3+0]=A0;
        out[(size_t)ray*3+1]=A1;
        out[(size_t)ray*3+2]=A2;
        out[(size_t)NR*3 + (size_t)ray]=AD;
    }
}

__global__ void transpose_mats(const float* __restrict__ in, float* __restrict__ out, int total){
    const int idx = blockIdx.x*blockDim.x+threadIdx.x;
    if (idx < total){
        const int pix = idx % 2304;
        const int c   = (idx / 2304) & 31;
        const int ib  = idx / (2304*32);
        out[((size_t)ib*2304+pix)*32 + c] = in[idx];
    }
}

__global__ void transpose_vecs(const float* __restrict__ in, float* __restrict__ out, int total){
    const int idx = blockIdx.x*blockDim.x+threadIdx.x;
    if (idx < total){
        const int r  = idx % 48;
        const int c  = (idx / 48) & 31;
        const int ib = idx / (48*32);
        out[((size_t)ib*48+r)*32 + c] = in[idx];
    }
}

// wT[n][k] (64x96 f16, zero-pad k>=72) and w1T[n][k] (64x64 f16)
__global__ void prep_weights(const float* __restrict__ w_mat, const float* __restrict__ w1,
                             f16* __restrict__ wT, f16* __restrict__ w1T){
    const int idx = blockIdx.x*blockDim.x + threadIdx.x;
    if (idx < 64*96){
        const int n = idx / 96, k = idx % 96;
        wT[idx] = (k < 72) ? (f16)w_mat[k*64+n] : (f16)0.0f;
    } else if (idx < 64*96 + 64*64){
        const int i2 = idx - 64*96;
        const int n = i2 / 64, k = i2 % 64;
        w1T[i2] = (f16)w1[k*64+n];
    }
}

extern "C" void kernel_launch(void* const* d_in, const int* in_sizes, int n_in,
                              void* d_out, int out_size, void* d_ws, size_t ws_size,
                              hipStream_t stream) {
    const float* rays_o  = (const float*)d_in[0];
    const float* rays_d  = (const float*)d_in[1];
    const float* matrixs = (const float*)d_in[2];
    const float* vectors = (const float*)d_in[3];
    const float* w_mat   = (const float*)d_in[4];
    const float* b_mat   = (const float*)d_in[5];
    const float* w1      = (const float*)d_in[6];
    const float* b1      = (const float*)d_in[7];
    const float* w2      = (const float*)d_in[8];
    const float* b2      = (const float*)d_in[9];
    float* out = (float*)d_out;

    const int B = in_sizes[2] / (3*32*48*48);
    const int R = (in_sizes[0]/3) / B;
    const int NR = B*R;

    const int matsz = 3*B*32*2304;
    const int vecsz = 3*B*32*48;
    const size_t need_full = ((size_t)matsz + (size_t)vecsz)*sizeof(float) + (size_t)(64*96+64*64)*sizeof(f16);
    const size_t need_w    = (size_t)(64*96+64*64)*sizeof(f16);

    const int nblk = (NR + WAVES-1)/WAVES;
    const int nthr = WAVES*64;

    if (ws_size >= need_full){
        float* tm = (float*)d_ws;
        float* tv = tm + matsz;
        f16* wT  = (f16*)(tv + vecsz);
        f16* w1T = wT + 64*96;
        transpose_mats<<<(matsz+255)/256, 256, 0, stream>>>(matrixs, tm, matsz);
        transpose_vecs<<<(vecsz+255)/256, 256, 0, stream>>>(vectors, tv, vecsz);
        prep_weights<<<(64*96+64*64+255)/256, 256, 0, stream>>>(w_mat, w1, wT, w1T);
        render_kernel<true><<<nblk, nthr, 0, stream>>>(rays_o, rays_d, tm, tv,
            wT, b_mat, w1T, b1, w1, w2, b2, out, B, R);
    } else if (ws_size >= need_w){
        f16* wT  = (f16*)d_ws;
        f16* w1T = wT + 64*96;
        prep_weights<<<(64*96+64*64+255)/256, 256, 0, stream>>>(w_mat, w1, wT, w1T);
        render_kernel<false><<<nblk, nthr, 0, stream>>>(rays_o, rays_d, matrixs, vectors,
            wT, b_mat, w1T, b1, w1, w2, b2, out, B, R);
    }
}

// Round 8
// 298.199 us; speedup vs baseline: 344.0195x; 1.5532x over previous
//
#include <hip/hip_runtime.h>
#include <math.h>

#define NSMP 48
#define FSTR 104   // feat row stride in f16 (96 K-padded + 8; 208B, 16B-aligned)
#define HSTR 72    // hid row stride in f16 (64 + 8 pad; 144B, 16B-aligned)
#define WAVES 3
#define LUTN 256   // gelu LUT entries over [-8,8], step 1/16

typedef _Float16 f16;
typedef _Float16 half8 __attribute__((ext_vector_type(8)));
typedef _Float16 half4 __attribute__((ext_vector_type(4)));
typedef _Float16 h2    __attribute__((ext_vector_type(2)));
typedef float    f32x4 __attribute__((ext_vector_type(4)));

__device__ __forceinline__ float sigmoid_f(float x){
    return __builtin_amdgcn_rcpf(1.0f + __expf(-x));
}
// gelu via LDS LUT: x * lerp(Phi) ; ~9 VALU + 1 ds_read_b64 (pipe-parallel)
__device__ __forceinline__ float gelu_lut(float x, const float2* __restrict__ lut){
    float u = __builtin_fmaf(x, 16.0f, 128.0f);
    u = fminf(fmaxf(u, 0.0f), 255.0f);
    const float fi = floorf(u);
    const float2 e = lut[(int)fi];
    return x * __builtin_fmaf(u - fi, e.y, e.x);
}
// wave-synchronous LDS fence (per-wave LDS regions)
#define LDS_FENCE() asm volatile("s_waitcnt lgkmcnt(0)" ::: "memory")

template<bool TR>
__global__ __launch_bounds__(WAVES*64, 4)
void render_kernel(const float* __restrict__ rays_o,
                   const float* __restrict__ rays_d,
                   const f16*   __restrict__ mats16,  // TR: [ib][pix][32] f16
                   const f16*   __restrict__ vecs16,  // TR: [ib][r][32] f16
                   const float* __restrict__ matsf,   // !TR: original f32 layout
                   const float* __restrict__ vecsf,
                   const f16*   __restrict__ wT,      // [64][96] f16, 0-pad k>=72
                   const float* __restrict__ g_bmat,
                   const f16*   __restrict__ w1T,     // [64][64] f16
                   const float* __restrict__ g_b1,
                   const float* __restrict__ g_w1,    // f32 w1 (PE rows 64..90)
                   const float* __restrict__ g_w2,
                   const float* __restrict__ g_b2,
                   float* __restrict__ out, int B, int R)
{
    __shared__ f16 s_buf[WAVES][NSMP*FSTR];   // 29952 B (feat, then hid overlays)
    __shared__ float2 s_lut[LUTN];            // 2048 B

    const int tid  = threadIdx.x;

    // build gelu LUT (block-shared), BEFORE any wave can exit
    for (int i = tid; i < LUTN; i += WAVES*64){
        const float x0 = -8.0f + (float)i * 0.0625f;
        const float p0 = 0.5f*(1.0f + erff( x0          *0.70710678118654752f));
        const float p1 = 0.5f*(1.0f + erff((x0+0.0625f) *0.70710678118654752f));
        float2 e; e.x = p0; e.y = p1 - p0;
        s_lut[i] = e;
    }
    __syncthreads();
    const float2* lut = s_lut;

    const int wv   = tid >> 6;
    const int lane = tid & 63;
    const int NR   = B*R;
    const int ray  = blockIdx.x*WAVES + wv;
    if (ray >= NR) return;                    // wave-uniform exit (after barrier)
    const int b = ray / R;

    f16* gF = s_buf[wv];
    f16* gH = s_buf[wv];                      // overlay

    const float ox=rays_o[ray*3+0], oy=rays_o[ray*3+1], oz=rays_o[ray*3+2];
    const float dx=rays_d[ray*3+0], dy=rays_d[ray*3+1], dz=rays_d[ray*3+2];

    // ================= Phase 1: gather (lane = sample) =================
    const int  s      = lane;
    const bool active = (s < NSMP);
    const int  sc     = active ? s : (NSMP-1);
    const float mid   = ((float)s  + 0.5f) * 0.03125f;
    const float midc  = ((float)sc + 0.5f) * 0.03125f;

    const float x0c = 1.25f*(ox + dx*midc);
    const float x1c = 1.25f*(oy + dy*midc);
    const float x2c = 1.25f*(oz + dz*midc);

    float sigma = 0.0f;

    #pragma unroll 1
    for (int i=0;i<3;i++){
        // MAT_MODE = {{0,1},{2,0},{1,2}}, VEC_MODE = {2,1,0}
        const float cx = (i==0)? x0c : (i==1)? x2c : x1c;
        const float cy = (i==0)? x1c : (i==1)? x0c : x2c;
        const float cv = (i==0)? x2c : (i==1)? x1c : x0c;

        const float px = (cx+1.0f)*23.5f;
        const float py = (cy+1.0f)*23.5f;
        const float fx0 = floorf(px), fy0 = floorf(py);
        const float wx = px-fx0, wy = py-fy0;
        const int ix0 = (int)fx0, iy0 = (int)fy0;

        int   toff[4];
        float tw[4];
        #pragma unroll
        for (int t=0;t<4;t++){
            const int xx = ix0 + (t&1);
            const int yy = iy0 + (t>>1);
            const bool inb = (xx>=0)&&(xx<48)&&(yy>=0)&&(yy<48);
            const int xcl = min(max(xx,0),47);
            const int ycl = min(max(yy,0),47);
            toff[t] = ycl*48+xcl;
            const float wxx = (t&1)? wx : 1.0f-wx;
            const float wyy = (t>>1)? wy : 1.0f-wy;
            tw[t] = inb ? wxx*wyy : 0.0f;
        }

        const float pv = (cv+1.0f)*23.5f;
        const float fp0 = floorf(pv);
        const float wvv = pv-fp0;
        const int ip0 = (int)fp0;
        int voff[2]; float vw[2];
        #pragma unroll
        for (int t=0;t<2;t++){
            const int pp = ip0+t;
            const bool inb = (pp>=0)&&(pp<48);
            voff[t] = min(max(pp,0),47);
            vw[t] = inb ? ((t)? wvv : 1.0f-wvv) : 0.0f;
        }

        if (TR){
            const f16* pb = mats16 + ((size_t)(i*B+b))*(2304u*32u);
            const f16* vb = vecs16 + ((size_t)(i*B+b))*(48u*32u);
            const half8* t0 = (const half8*)(pb + toff[0]*32);
            const half8* t1 = (const half8*)(pb + toff[1]*32);
            const half8* t2 = (const half8*)(pb + toff[2]*32);
            const half8* t3 = (const half8*)(pb + toff[3]*32);
            const half8* v0 = (const half8*)(vb + voff[0]*32);
            const half8* v1 = (const half8*)(vb + voff[1]*32);

            const h2 tw0h = {(f16)tw[0],(f16)tw[0]};
            const h2 tw1h = {(f16)tw[1],(f16)tw[1]};
            const h2 tw2h = {(f16)tw[2],(f16)tw[2]};
            const h2 tw3h = {(f16)tw[3],(f16)tw[3]};
            const h2 vw0h = {(f16)vw[0],(f16)vw[0]};
            const h2 vw1h = {(f16)vw[1],(f16)vw[1]};

            // 8 channels per iter, packed-f16 blend
            #pragma unroll 2
            for (int c4=0;c4<4;c4++){
                const half8 a0=t0[c4], a1=t1[c4], a2=t2[c4], a3=t3[c4];
                const half8 q0=v0[c4], q1=v1[c4];
                float g[8];
                #pragma unroll
                for (int j=0;j<4;j++){
                    const h2 a0j = {a0[2*j], a0[2*j+1]};
                    const h2 a1j = {a1[2*j], a1[2*j+1]};
                    const h2 a2j = {a2[2*j], a2[2*j+1]};
                    const h2 a3j = {a3[2*j], a3[2*j+1]};
                    const h2 q0j = {q0[2*j], q0[2*j+1]};
                    const h2 q1j = {q1[2*j], q1[2*j+1]};
                    h2 pf = a0j*tw0h; pf += a1j*tw1h; pf += a2j*tw2h; pf += a3j*tw3h;
                    h2 vf = q0j*vw0h; vf += q1j*vw1h;
                    const h2 fj = pf*vf;
                    if (c4==0){
                        sigma += (float)fj[0] + (float)fj[1];
                    } else {
                        g[2*j]   = gelu_lut((float)fj[0], lut);
                        g[2*j+1] = gelu_lut((float)fj[1], lut);
                    }
                }
                if (c4>0 && active){
                    half8 hv = {(f16)g[0],(f16)g[1],(f16)g[2],(f16)g[3],
                                (f16)g[4],(f16)g[5],(f16)g[6],(f16)g[7]};
                    *(half8*)(gF + s*FSTR + i*24 + c4*8 - 8) = hv;
                }
            }
        } else {
            const float* pb = matsf + ((size_t)(i*B+b))*(32u*2304u);
            const float* vb = vecsf + ((size_t)(i*B+b))*(32u*48u);
            #pragma unroll 2
            for (int c=0;c<32;c++){
                const float* fc = pb + c*2304;
                const float pf = tw[0]*fc[toff[0]] + tw[1]*fc[toff[1]]
                               + tw[2]*fc[toff[2]] + tw[3]*fc[toff[3]];
                const float* vc = vb + c*48;
                const float vf = vw[0]*vc[voff[0]] + vw[1]*vc[voff[1]];
                const float r = pf*vf;
                if (c < 8) sigma += r;
                else if (active) gF[s*FSTR + i*24 + c - 8] = (f16)gelu_lut(r, lut);
            }
        }
    }
    // zero the K-pad region (k = 72..95)
    if (active){
        half8 z8 = {0,0,0,0,0,0,0,0};
        *(half8*)(gF + s*FSTR + 72) = z8;
        *(half8*)(gF + s*FSTR + 80) = z8;
        *(half8*)(gF + s*FSTR + 88) = z8;
    }

    const int q  = lane >> 4;   // quad
    const int cl = lane & 15;   // col index within tile

    // ======== Phase 2: layer-1 GEMM  hid^T(64x48) = wT(64x96) @ feat^T(96x48) ========
    f32x4 acc[4][3];
    #pragma unroll
    for (int mt=0;mt<4;mt++){
        const float4 bmv = *(const float4*)(g_bmat + mt*16 + q*4);
        #pragma unroll
        for (int nt=0;nt<3;nt++){
            acc[mt][nt][0]=bmv.x; acc[mt][nt][1]=bmv.y; acc[mt][nt][2]=bmv.z; acc[mt][nt][3]=bmv.w;
        }
    }

    LDS_FENCE();   // feat writes visible to whole wave

    #pragma unroll 1
    for (int ks=0; ks<3; ks++){
        half8 bf[3];
        #pragma unroll
        for (int nt=0;nt<3;nt++)
            bf[nt] = *(const half8*)(gF + (nt*16+cl)*FSTR + ks*32 + q*8);
        #pragma unroll
        for (int mt=0;mt<4;mt++){
            const half8 af = *(const half8*)(wT + (mt*16+cl)*96 + ks*32 + q*8);
            #pragma unroll
            for (int nt=0;nt<3;nt++)
                acc[mt][nt] = __builtin_amdgcn_mfma_f32_16x16x32_f16(af, bf[nt], acc[mt][nt], 0,0,0);
        }
    }

    // gelu + pack + store hid^T into the SAME LDS region
    LDS_FENCE();   // all feat reads drained before overwrite
    #pragma unroll
    for (int mt=0;mt<4;mt++){
        #pragma unroll
        for (int nt=0;nt<3;nt++){
            half4 hv = {(f16)gelu_lut(acc[mt][nt][0], lut), (f16)gelu_lut(acc[mt][nt][1], lut),
                        (f16)gelu_lut(acc[mt][nt][2], lut), (f16)gelu_lut(acc[mt][nt][3], lut)};
            *(half4*)(gH + (nt*16+cl)*HSTR + mt*16 + q*4) = hv;
        }
    }

    // ================= Phase 3: PE fold (lane = hidden j) =================
    float pe = g_b1[lane];
    {
        const float inv_n = rsqrtf(dx*dx+dy*dy+dz*dz);
        const float vd0=dx*inv_n, vd1=dy*inv_n, vd2=dz*inv_n;
        pe += vd0*g_w1[64*64+lane] + vd1*g_w1[65*64+lane] + vd2*g_w1[66*64+lane];
        #pragma unroll 1
        for (int fq=0; fq<4; fq++){
            const float fs = (float)(1<<fq);
            pe += __sinf(vd0*fs)*g_w1[(67+fq*3+0)*64+lane];
            pe += __sinf(vd1*fs)*g_w1[(67+fq*3+1)*64+lane];
            pe += __sinf(vd2*fs)*g_w1[(67+fq*3+2)*64+lane];
            pe += __cosf(vd0*fs)*g_w1[(79+fq*3+0)*64+lane];
            pe += __cosf(vd1*fs)*g_w1[(79+fq*3+1)*64+lane];
            pe += __cosf(vd2*fs)*g_w1[(79+fq*3+2)*64+lane];
        }
    }

    // ======== Phase 4: layer-2 GEMM  h2^T(64x48) = w1T(64x64) @ hid^T(64x48) ========
    f32x4 acc2[4][3];
    #pragma unroll
    for (int mt=0;mt<4;mt++){
        const float p0 = __shfl(pe, mt*16+q*4+0, 64);
        const float p1 = __shfl(pe, mt*16+q*4+1, 64);
        const float p2 = __shfl(pe, mt*16+q*4+2, 64);
        const float p3 = __shfl(pe, mt*16+q*4+3, 64);
        #pragma unroll
        for (int nt=0;nt<3;nt++){
            acc2[mt][nt][0]=p0; acc2[mt][nt][1]=p1; acc2[mt][nt][2]=p2; acc2[mt][nt][3]=p3;
        }
    }

    LDS_FENCE();   // hid writes visible

    #pragma unroll 1
    for (int ks=0; ks<2; ks++){
        half8 bf[3];
        #pragma unroll
        for (int nt=0;nt<3;nt++)
            bf[nt] = *(const half8*)(gH + (nt*16+cl)*HSTR + ks*32 + q*8);
        #pragma unroll
        for (int mt=0;mt<4;mt++){
            const half8 af = *(const half8*)(w1T + (mt*16+cl)*64 + ks*32 + q*8);
            #pragma unroll
            for (int nt=0;nt<3;nt++)
                acc2[mt][nt] = __builtin_amdgcn_mfma_f32_16x16x32_f16(af, bf[nt], acc2[mt][nt], 0,0,0);
        }
    }

    // ======== Phase 5: layer 3 + sigmoid, straight from C-registers ========
    const float b20=g_b2[0], b21=g_b2[1], b22=g_b2[2];
    float rgb0=0.0f, rgb1=0.0f, rgb2=0.0f;
    #pragma unroll
    for (int nt=0;nt<3;nt++){
        float r0=0.0f, r1=0.0f, r2=0.0f;
        #pragma unroll
        for (int mt=0;mt<4;mt++){
            const float4* wp = (const float4*)(g_w2 + (size_t)(mt*16+q*4)*3);
            const float4 wa = wp[0], wb = wp[1], wc = wp[2];
            const float g0 = gelu_lut(acc2[mt][nt][0], lut);
            const float g1 = gelu_lut(acc2[mt][nt][1], lut);
            const float g2 = gelu_lut(acc2[mt][nt][2], lut);
            const float g3 = gelu_lut(acc2[mt][nt][3], lut);
            r0 += g0*wa.x + g1*wa.w + g2*wb.z + g3*wc.y;
            r1 += g0*wa.y + g1*wb.x + g2*wb.w + g3*wc.z;
            r2 += g0*wa.z + g1*wb.y + g2*wc.x + g3*wc.w;
        }
        r0 += __shfl_xor(r0, 16, 64);  r0 += __shfl_xor(r0, 32, 64);
        r1 += __shfl_xor(r1, 16, 64);  r1 += __shfl_xor(r1, 32, 64);
        r2 += __shfl_xor(r2, 16, 64);  r2 += __shfl_xor(r2, 32, 64);
        if (q == nt){
            rgb0 = sigmoid_f(r0+b20);
            rgb1 = sigmoid_f(r1+b21);
            rgb2 = sigmoid_f(r2+b22);
        }
    }

    // ======== Phase 6: volume integration (lane = sample) ========
    const float sg    = fmaxf(sigma, 0.0f);
    const float alpha = active ? (1.0f - __expf(-sg*0.03125f)) : 0.0f;
    float v = active ? (1.0f - alpha + 1e-10f) : 1.0f;
    #pragma unroll
    for (int off=1; off<64; off<<=1){
        const float up = __shfl_up(v, off, 64);
        if (lane >= off) v *= up;
    }
    float T = __shfl_up(v, 1, 64);
    if (lane==0) T = 1.0f;
    const float w = alpha*T;

    if (active) out[(size_t)NR*4 + (size_t)ray*NSMP + s] = w;

    float A0=w*rgb0, A1=w*rgb1, A2=w*rgb2, AD=w*mid;
    #pragma unroll
    for (int off=32; off>0; off>>=1){
        A0 += __shfl_down(A0, off, 64);
        A1 += __shfl_down(A1, off, 64);
        A2 += __shfl_down(A2, off, 64);
        AD += __shfl_down(AD, off, 64);
    }
    if (lane==0){
        out[(size_t)ray*3+0]=A0;
        out[(size_t)ray*3+1]=A1;
        out[(size_t)ray*3+2]=A2;
        out[(size_t)NR*3 + (size_t)ray]=AD;
    }
}

__global__ void transpose_mats(const float* __restrict__ in, f16* __restrict__ out, int total){
    const int idx = blockIdx.x*blockDim.x+threadIdx.x;
    if (idx < total){
        const int pix = idx % 2304;
        const int c   = (idx / 2304) & 31;
        const int ib  = idx / (2304*32);
        out[((size_t)ib*2304+pix)*32 + c] = (f16)in[idx];
    }
}

__global__ void transpose_vecs(const float* __restrict__ in, f16* __restrict__ out, int total){
    const int idx = blockIdx.x*blockDim.x+threadIdx.x;
    if (idx < total){
        const int r  = idx % 48;
        const int c  = (idx / 48) & 31;
        const int ib = idx / (48*32);
        out[((size_t)ib*48+r)*32 + c] = (f16)in[idx];
    }
}

// wT[n][k] (64x96 f16, zero-pad k>=72) and w1T[n][k] (64x64 f16)
__global__ void prep_weights(const float* __restrict__ w_mat, const float* __restrict__ w1,
                             f16* __restrict__ wT, f16* __restrict__ w1T){
    const int idx = blockIdx.x*blockDim.x + threadIdx.x;
    if (idx < 64*96){
        const int n = idx / 96, k = idx % 96;
        wT[idx] = (k < 72) ? (f16)w_mat[k*64+n] : (f16)0.0f;
    } else if (idx < 64*96 + 64*64){
        const int i2 = idx - 64*96;
        const int n = i2 / 64, k = i2 % 64;
        w1T[i2] = (f16)w1[k*64+n];
    }
}

extern "C" void kernel_launch(void* const* d_in, const int* in_sizes, int n_in,
                              void* d_out, int out_size, void* d_ws, size_t ws_size,
                              hipStream_t stream) {
    const float* rays_o  = (const float*)d_in[0];
    const float* rays_d  = (const float*)d_in[1];
    const float* matrixs = (const float*)d_in[2];
    const float* vectors = (const float*)d_in[3];
    const float* w_mat   = (const float*)d_in[4];
    const float* b_mat   = (const float*)d_in[5];
    const float* w1      = (const float*)d_in[6];
    const float* b1      = (const float*)d_in[7];
    const float* w2      = (const float*)d_in[8];
    const float* b2      = (const float*)d_in[9];
    float* out = (float*)d_out;

    const int B = in_sizes[2] / (3*32*48*48);
    const int R = (in_sizes[0]/3) / B;
    const int NR = B*R;

    const int matsz = 3*B*32*2304;
    const int vecsz = 3*B*32*48;
    const size_t need_full = ((size_t)matsz + (size_t)vecsz)*sizeof(f16)
                           + (size_t)(64*96+64*64)*sizeof(f16);
    const size_t need_w    = (size_t)(64*96+64*64)*sizeof(f16);

    const int nblk = (NR + WAVES-1)/WAVES;
    const int nthr = WAVES*64;

    if (ws_size >= need_full){
        f16* tm  = (f16*)d_ws;
        f16* tv  = tm + matsz;
        f16* wT  = tv + vecsz;
        f16* w1T = wT + 64*96;
        transpose_mats<<<(matsz+255)/256, 256, 0, stream>>>(matrixs, tm, matsz);
        transpose_vecs<<<(vecsz+255)/256, 256, 0, stream>>>(vectors, tv, vecsz);
        prep_weights<<<(64*96+64*64+255)/256, 256, 0, stream>>>(w_mat, w1, wT, w1T);
        render_kernel<true><<<nblk, nthr, 0, stream>>>(rays_o, rays_d, tm, tv,
            nullptr, nullptr, wT, b_mat, w1T, b1, w1, w2, b2, out, B, R);
    } else if (ws_size >= need_w){
        f16* wT  = (f16*)d_ws;
        f16* w1T = wT + 64*96;
        prep_weights<<<(64*96+64*64+255)/256, 256, 0, stream>>>(w_mat, w1, wT, w1T);
        render_kernel<false><<<nblk, nthr, 0, stream>>>(rays_o, rays_d,
            nullptr, nullptr, matrixs, vectors, wT, b_mat, w1T, b1, w1, w2, b2, out, B, R);
    }
}

// Round 9
// 296.131 us; speedup vs baseline: 346.4228x; 1.0070x over previous
//
#include <hip/hip_runtime.h>
#include <math.h>

#define NSMP 48
#define FSTR 104   // feat row stride in f16 (96 K-padded + 8; 208B, 16B-aligned)
#define HSTR 72    // hid row stride in f16 (64 + 8 pad; 144B, 16B-aligned)
#define WAVES 2
#define LUTN 256   // gelu LUT entries over [-8,8], step 1/16

typedef _Float16 f16;
typedef _Float16 half8 __attribute__((ext_vector_type(8)));
typedef _Float16 half4 __attribute__((ext_vector_type(4)));
typedef _Float16 h2    __attribute__((ext_vector_type(2)));
typedef float    f32x4 __attribute__((ext_vector_type(4)));

__device__ __forceinline__ float sigmoid_f(float x){
    return __builtin_amdgcn_rcpf(1.0f + __expf(-x));
}
// gelu via LDS LUT: x * lerp(Phi); u>=0 after clamp so trunc==floor
__device__ __forceinline__ float gelu_lut(float x, const float2* __restrict__ lut){
    float u = __builtin_fmaf(x, 16.0f, 128.0f);
    u = fminf(fmaxf(u, 0.0f), 255.0f);
    const int   i  = (int)u;
    const float fi = (float)i;
    const float2 e = lut[i];
    return x * __builtin_fmaf(u - fi, e.y, e.x);
}
// wave-synchronous LDS fence (per-wave LDS regions)
#define LDS_FENCE() asm volatile("s_waitcnt lgkmcnt(0)" ::: "memory")

template<bool TR>
__global__ __launch_bounds__(WAVES*64, 4)
void render_kernel(const float* __restrict__ rays_o,
                   const float* __restrict__ rays_d,
                   const f16*   __restrict__ mats16,  // TR: [ib][pix][32] f16
                   const f16*   __restrict__ vecs16,  // TR: [ib][r][32] f16
                   const float* __restrict__ matsf,   // !TR: original f32 layout
                   const float* __restrict__ vecsf,
                   const f16*   __restrict__ wT,      // [64][96] f16, 0-pad k>=72
                   const float* __restrict__ g_bmat,
                   const f16*   __restrict__ w1T,     // [64][64] f16
                   const float* __restrict__ g_b1,
                   const float* __restrict__ g_w1,    // f32 w1 (PE rows 64..90)
                   const float* __restrict__ g_w2,
                   const float* __restrict__ g_b2,
                   float* __restrict__ out, int B, int R)
{
    __shared__ f16 s_buf[WAVES][NSMP*FSTR];   // 19968 B (feat, then hid overlays)
    __shared__ float2 s_lut[LUTN];            // 2048 B

    const int tid  = threadIdx.x;

    // build gelu LUT (block-shared), BEFORE any wave can exit
    for (int i = tid; i < LUTN; i += WAVES*64){
        const float x0 = -8.0f + (float)i * 0.0625f;
        const float p0 = 0.5f*(1.0f + erff( x0          *0.70710678118654752f));
        const float p1 = 0.5f*(1.0f + erff((x0+0.0625f) *0.70710678118654752f));
        float2 e; e.x = p0; e.y = p1 - p0;
        s_lut[i] = e;
    }
    __syncthreads();
    const float2* lut = s_lut;

    const int wv   = tid >> 6;
    const int lane = tid & 63;
    const int NR   = B*R;
    const int ray  = blockIdx.x*WAVES + wv;
    if (ray >= NR) return;                    // wave-uniform exit (after barrier)
    const int b = ray / R;

    f16* gF = s_buf[wv];
    f16* gH = s_buf[wv];                      // overlay

    const float ox=rays_o[ray*3+0], oy=rays_o[ray*3+1], oz=rays_o[ray*3+2];
    const float dx=rays_d[ray*3+0], dy=rays_d[ray*3+1], dz=rays_d[ray*3+2];

    // ================= Phase 1: gather (lane = sample) =================
    const int  s      = lane;
    const bool active = (s < NSMP);
    const int  sc     = active ? s : (NSMP-1);
    const float mid   = ((float)s  + 0.5f) * 0.03125f;
    const float midc  = ((float)sc + 0.5f) * 0.03125f;

    const float x0c = 1.25f*(ox + dx*midc);
    const float x1c = 1.25f*(oy + dy*midc);
    const float x2c = 1.25f*(oz + dz*midc);

    float sigma = 0.0f;

    #pragma unroll 1
    for (int i=0;i<3;i++){
        // MAT_MODE = {{0,1},{2,0},{1,2}}, VEC_MODE = {2,1,0}
        const float cx = (i==0)? x0c : (i==1)? x2c : x1c;
        const float cy = (i==0)? x1c : (i==1)? x0c : x2c;
        const float cv = (i==0)? x2c : (i==1)? x1c : x0c;

        const float px = (cx+1.0f)*23.5f;
        const float py = (cy+1.0f)*23.5f;
        const float fx0 = floorf(px), fy0 = floorf(py);
        const float wx = px-fx0, wy = py-fy0;
        const int ix0 = (int)fx0, iy0 = (int)fy0;

        int   toff[4];
        float tw[4];
        #pragma unroll
        for (int t=0;t<4;t++){
            const int xx = ix0 + (t&1);
            const int yy = iy0 + (t>>1);
            const bool inb = (xx>=0)&&(xx<48)&&(yy>=0)&&(yy<48);
            const int xcl = min(max(xx,0),47);
            const int ycl = min(max(yy,0),47);
            toff[t] = ycl*48+xcl;
            const float wxx = (t&1)? wx : 1.0f-wx;
            const float wyy = (t>>1)? wy : 1.0f-wy;
            tw[t] = inb ? wxx*wyy : 0.0f;
        }

        const float pv = (cv+1.0f)*23.5f;
        const float fp0 = floorf(pv);
        const float wvv = pv-fp0;
        const int ip0 = (int)fp0;
        int voff[2]; float vw[2];
        #pragma unroll
        for (int t=0;t<2;t++){
            const int pp = ip0+t;
            const bool inb = (pp>=0)&&(pp<48);
            voff[t] = min(max(pp,0),47);
            vw[t] = inb ? ((t)? wvv : 1.0f-wvv) : 0.0f;
        }

        if (TR){
            const f16* pb = mats16 + ((size_t)(i*B+b))*(2304u*32u);
            const f16* vb = vecs16 + ((size_t)(i*B+b))*(48u*32u);
            const half8* t0 = (const half8*)(pb + toff[0]*32);
            const half8* t1 = (const half8*)(pb + toff[1]*32);
            const half8* t2 = (const half8*)(pb + toff[2]*32);
            const half8* t3 = (const half8*)(pb + toff[3]*32);
            const half8* v0 = (const half8*)(vb + voff[0]*32);
            const half8* v1 = (const half8*)(vb + voff[1]*32);

            const h2 tw0h = {(f16)tw[0],(f16)tw[0]};
            const h2 tw1h = {(f16)tw[1],(f16)tw[1]};
            const h2 tw2h = {(f16)tw[2],(f16)tw[2]};
            const h2 tw3h = {(f16)tw[3],(f16)tw[3]};
            const h2 vw0h = {(f16)vw[0],(f16)vw[0]};
            const h2 vw1h = {(f16)vw[1],(f16)vw[1]};

            // 8 channels per iter, packed-f16 blend
            #pragma unroll 2
            for (int c4=0;c4<4;c4++){
                const half8 a0=t0[c4], a1=t1[c4], a2=t2[c4], a3=t3[c4];
                const half8 q0=v0[c4], q1=v1[c4];
                float g[8];
                #pragma unroll
                for (int j=0;j<4;j++){
                    const h2 a0j = {a0[2*j], a0[2*j+1]};
                    const h2 a1j = {a1[2*j], a1[2*j+1]};
                    const h2 a2j = {a2[2*j], a2[2*j+1]};
                    const h2 a3j = {a3[2*j], a3[2*j+1]};
                    const h2 q0j = {q0[2*j], q0[2*j+1]};
                    const h2 q1j = {q1[2*j], q1[2*j+1]};
                    h2 pf = a0j*tw0h; pf += a1j*tw1h; pf += a2j*tw2h; pf += a3j*tw3h;
                    h2 vf = q0j*vw0h; vf += q1j*vw1h;
                    const h2 fj = pf*vf;
                    if (c4==0){
                        sigma += (float)fj[0] + (float)fj[1];
                    } else {
                        g[2*j]   = gelu_lut((float)fj[0], lut);
                        g[2*j+1] = gelu_lut((float)fj[1], lut);
                    }
                }
                if (c4>0 && active){
                    half8 hv = {(f16)g[0],(f16)g[1],(f16)g[2],(f16)g[3],
                                (f16)g[4],(f16)g[5],(f16)g[6],(f16)g[7]};
                    *(half8*)(gF + s*FSTR + i*24 + c4*8 - 8) = hv;
                }
            }
        } else {
            const float* pb = matsf + ((size_t)(i*B+b))*(32u*2304u);
            const float* vb = vecsf + ((size_t)(i*B+b))*(32u*48u);
            #pragma unroll 2
            for (int c=0;c<32;c++){
                const float* fc = pb + c*2304;
                const float pf = tw[0]*fc[toff[0]] + tw[1]*fc[toff[1]]
                               + tw[2]*fc[toff[2]] + tw[3]*fc[toff[3]];
                const float* vc = vb + c*48;
                const float vf = vw[0]*vc[voff[0]] + vw[1]*vc[voff[1]];
                const float r = pf*vf;
                if (c < 8) sigma += r;
                else if (active) gF[s*FSTR + i*24 + c - 8] = (f16)gelu_lut(r, lut);
            }
        }
    }
    // zero the K-pad region (k = 72..95)
    if (active){
        half8 z8 = {0,0,0,0,0,0,0,0};
        *(half8*)(gF + s*FSTR + 72) = z8;
        *(half8*)(gF + s*FSTR + 80) = z8;
        *(half8*)(gF + s*FSTR + 88) = z8;
    }

    const int q  = lane >> 4;   // quad
    const int cl = lane & 15;   // col index within tile

    // ======== Phase 2: layer-1 GEMM  hid^T(64x48) = wT(64x96) @ feat^T(96x48) ========
    f32x4 acc[4][3];
    #pragma unroll
    for (int mt=0;mt<4;mt++){
        const float4 bmv = *(const float4*)(g_bmat + mt*16 + q*4);
        #pragma unroll
        for (int nt=0;nt<3;nt++){
            acc[mt][nt][0]=bmv.x; acc[mt][nt][1]=bmv.y; acc[mt][nt][2]=bmv.z; acc[mt][nt][3]=bmv.w;
        }
    }

    LDS_FENCE();   // feat writes visible to whole wave

    #pragma unroll 1
    for (int ks=0; ks<3; ks++){
        half8 bf[3];
        #pragma unroll
        for (int nt=0;nt<3;nt++)
            bf[nt] = *(const half8*)(gF + (nt*16+cl)*FSTR + ks*32 + q*8);
        #pragma unroll
        for (int mt=0;mt<4;mt++){
            const half8 af = *(const half8*)(wT + (mt*16+cl)*96 + ks*32 + q*8);
            #pragma unroll
            for (int nt=0;nt<3;nt++)
                acc[mt][nt] = __builtin_amdgcn_mfma_f32_16x16x32_f16(af, bf[nt], acc[mt][nt], 0,0,0);
        }
    }

    // gelu + pack + store hid^T into the SAME LDS region
    LDS_FENCE();   // all feat reads drained before overwrite
    #pragma unroll
    for (int mt=0;mt<4;mt++){
        #pragma unroll
        for (int nt=0;nt<3;nt++){
            half4 hv = {(f16)gelu_lut(acc[mt][nt][0], lut), (f16)gelu_lut(acc[mt][nt][1], lut),
                        (f16)gelu_lut(acc[mt][nt][2], lut), (f16)gelu_lut(acc[mt][nt][3], lut)};
            *(half4*)(gH + (nt*16+cl)*HSTR + mt*16 + q*4) = hv;
        }
    }

    // ================= Phase 3: PE fold (lane = hidden j) =================
    float pe = g_b1[lane];
    {
        const float inv_n = rsqrtf(dx*dx+dy*dy+dz*dz);
        const float vd0=dx*inv_n, vd1=dy*inv_n, vd2=dz*inv_n;
        pe += vd0*g_w1[64*64+lane] + vd1*g_w1[65*64+lane] + vd2*g_w1[66*64+lane];
        #pragma unroll 1
        for (int fq=0; fq<4; fq++){
            const float fs = (float)(1<<fq);
            pe += __sinf(vd0*fs)*g_w1[(67+fq*3+0)*64+lane];
            pe += __sinf(vd1*fs)*g_w1[(67+fq*3+1)*64+lane];
            pe += __sinf(vd2*fs)*g_w1[(67+fq*3+2)*64+lane];
            pe += __cosf(vd0*fs)*g_w1[(79+fq*3+0)*64+lane];
            pe += __cosf(vd1*fs)*g_w1[(79+fq*3+1)*64+lane];
            pe += __cosf(vd2*fs)*g_w1[(79+fq*3+2)*64+lane];
        }
    }

    // ======== Phase 4: layer-2 GEMM  h2^T(64x48) = w1T(64x64) @ hid^T(64x48) ========
    f32x4 acc2[4][3];
    #pragma unroll
    for (int mt=0;mt<4;mt++){
        const float p0 = __shfl(pe, mt*16+q*4+0, 64);
        const float p1 = __shfl(pe, mt*16+q*4+1, 64);
        const float p2 = __shfl(pe, mt*16+q*4+2, 64);
        const float p3 = __shfl(pe, mt*16+q*4+3, 64);
        #pragma unroll
        for (int nt=0;nt<3;nt++){
            acc2[mt][nt][0]=p0; acc2[mt][nt][1]=p1; acc2[mt][nt][2]=p2; acc2[mt][nt][3]=p3;
        }
    }

    LDS_FENCE();   // hid writes visible

    #pragma unroll 1
    for (int ks=0; ks<2; ks++){
        half8 bf[3];
        #pragma unroll
        for (int nt=0;nt<3;nt++)
            bf[nt] = *(const half8*)(gH + (nt*16+cl)*HSTR + ks*32 + q*8);
        #pragma unroll
        for (int mt=0;mt<4;mt++){
            const half8 af = *(const half8*)(w1T + (mt*16+cl)*64 + ks*32 + q*8);
            #pragma unroll
            for (int nt=0;nt<3;nt++)
                acc2[mt][nt] = __builtin_amdgcn_mfma_f32_16x16x32_f16(af, bf[nt], acc2[mt][nt], 0,0,0);
        }
    }

    // ======== Phase 5: layer 3 + sigmoid, straight from C-registers ========
    const float b20=g_b2[0], b21=g_b2[1], b22=g_b2[2];
    float rgb0=0.0f, rgb1=0.0f, rgb2=0.0f;
    #pragma unroll
    for (int nt=0;nt<3;nt++){
        float r0=0.0f, r1=0.0f, r2=0.0f;
        #pragma unroll
        for (int mt=0;mt<4;mt++){
            const float4* wp = (const float4*)(g_w2 + (size_t)(mt*16+q*4)*3);
            const float4 wa = wp[0], wb = wp[1], wc = wp[2];
            const float g0 = gelu_lut(acc2[mt][nt][0], lut);
            const float g1 = gelu_lut(acc2[mt][nt][1], lut);
            const float g2 = gelu_lut(acc2[mt][nt][2], lut);
            const float g3 = gelu_lut(acc2[mt][nt][3], lut);
            r0 += g0*wa.x + g1*wa.w + g2*wb.z + g3*wc.y;
            r1 += g0*wa.y + g1*wb.x + g2*wb.w + g3*wc.z;
            r2 += g0*wa.z + g1*wb.y + g2*wc.x + g3*wc.w;
        }
        r0 += __shfl_xor(r0, 16, 64);  r0 += __shfl_xor(r0, 32, 64);
        r1 += __shfl_xor(r1, 16, 64);  r1 += __shfl_xor(r1, 32, 64);
        r2 += __shfl_xor(r2, 16, 64);  r2 += __shfl_xor(r2, 32, 64);
        if (q == nt){
            rgb0 = sigmoid_f(r0+b20);
            rgb1 = sigmoid_f(r1+b21);
            rgb2 = sigmoid_f(r2+b22);
        }
    }

    // ======== Phase 6: volume integration (lane = sample) ========
    const float sg    = fmaxf(sigma, 0.0f);
    const float alpha = active ? (1.0f - __expf(-sg*0.03125f)) : 0.0f;
    float v = active ? (1.0f - alpha + 1e-10f) : 1.0f;
    #pragma unroll
    for (int off=1; off<64; off<<=1){
        const float up = __shfl_up(v, off, 64);
        if (lane >= off) v *= up;
    }
    float T = __shfl_up(v, 1, 64);
    if (lane==0) T = 1.0f;
    const float w = alpha*T;

    if (active) out[(size_t)NR*4 + (size_t)ray*NSMP + s] = w;

    float A0=w*rgb0, A1=w*rgb1, A2=w*rgb2, AD=w*mid;
    #pragma unroll
    for (int off=32; off>0; off>>=1){
        A0 += __shfl_down(A0, off, 64);
        A1 += __shfl_down(A1, off, 64);
        A2 += __shfl_down(A2, off, 64);
        AD += __shfl_down(AD, off, 64);
    }
    if (lane==0){
        out[(size_t)ray*3+0]=A0;
        out[(size_t)ray*3+1]=A1;
        out[(size_t)ray*3+2]=A2;
        out[(size_t)NR*3 + (size_t)ray]=AD;
    }
}

// LDS-tiled transpose: in f32 [ib][32][2304] -> out f16 [ib][2304][32]
// grid (2304/32, 3*B), block 256. Coalesced reads (128B rows) and writes (64B rows).
__global__ __launch_bounds__(256)
void transpose_mats_tiled(const float* __restrict__ in, f16* __restrict__ out){
    __shared__ float tl[32][33];
    const int pix0 = blockIdx.x*32;
    const int ib   = blockIdx.y;
    const int tx = threadIdx.x & 31;
    const int ty = threadIdx.x >> 5;      // 0..7
    const float* src = in + (size_t)ib*32*2304;
    #pragma unroll
    for (int t=0;t<4;t++){
        const int c = ty + t*8;
        tl[c][tx] = src[(size_t)c*2304 + pix0 + tx];
    }
    __syncthreads();
    f16* dst = out + (size_t)ib*2304*32;
    #pragma unroll
    for (int t=0;t<4;t++){
        const int p = ty + t*8;
        dst[(size_t)(pix0+p)*32 + tx] = (f16)tl[tx][p];
    }
}

// fused small prep: vec transpose (f32 [ib][32][48] -> f16 [ib][48][32]) + weight prep
__global__ void prep_small(const float* __restrict__ vecs, const float* __restrict__ w_mat,
                           const float* __restrict__ w1,
                           f16* __restrict__ tv, f16* __restrict__ wT, f16* __restrict__ w1T,
                           int vecsz){
    const int idx = blockIdx.x*blockDim.x + threadIdx.x;
    if (idx < vecsz){
        const int r  = idx % 48;
        const int c  = (idx / 48) & 31;
        const int ib = idx / (48*32);
        tv[((size_t)ib*48+r)*32 + c] = (f16)vecs[idx];
    } else if (idx < vecsz + 64*96){
        const int i1 = idx - vecsz;
        const int n = i1 / 96, k = i1 % 96;
        wT[i1] = (k < 72) ? (f16)w_mat[k*64+n] : (f16)0.0f;
    } else if (idx < vecsz + 64*96 + 64*64){
        const int i2 = idx - vecsz - 64*96;
        const int n = i2 / 64, k = i2 % 64;
        w1T[i2] = (f16)w1[k*64+n];
    }
}

extern "C" void kernel_launch(void* const* d_in, const int* in_sizes, int n_in,
                              void* d_out, int out_size, void* d_ws, size_t ws_size,
                              hipStream_t stream) {
    const float* rays_o  = (const float*)d_in[0];
    const float* rays_d  = (const float*)d_in[1];
    const float* matrixs = (const float*)d_in[2];
    const float* vectors = (const float*)d_in[3];
    const float* w_mat   = (const float*)d_in[4];
    const float* b_mat   = (const float*)d_in[5];
    const float* w1      = (const float*)d_in[6];
    const float* b1      = (const float*)d_in[7];
    const float* w2      = (const float*)d_in[8];
    const float* b2      = (const float*)d_in[9];
    float* out = (float*)d_out;

    const int B = in_sizes[2] / (3*32*48*48);
    const int R = (in_sizes[0]/3) / B;
    const int NR = B*R;

    const int matsz = 3*B*32*2304;
    const int vecsz = 3*B*32*48;
    const size_t need_full = ((size_t)matsz + (size_t)vecsz)*sizeof(f16)
                           + (size_t)(64*96+64*64)*sizeof(f16);
    const size_t need_w    = (size_t)(64*96+64*64)*sizeof(f16);

    const int nblk = (NR + WAVES-1)/WAVES;
    const int nthr = WAVES*64;

    if (ws_size >= need_full){
        f16* tm  = (f16*)d_ws;
        f16* tv  = tm + matsz;
        f16* wT  = tv + vecsz;
        f16* w1T = wT + 64*96;
        dim3 tg(2304/32, 3*B);
        transpose_mats_tiled<<<tg, 256, 0, stream>>>(matrixs, tm);
        const int smalln = vecsz + 64*96 + 64*64;
        prep_small<<<(smalln+255)/256, 256, 0, stream>>>(vectors, w_mat, w1, tv, wT, w1T, vecsz);
        render_kernel<true><<<nblk, nthr, 0, stream>>>(rays_o, rays_d, tm, tv,
            nullptr, nullptr, wT, b_mat, w1T, b1, w1, w2, b2, out, B, R);
    } else if (ws_size >= need_w){
        f16* wT  = (f16*)d_ws;
        f16* w1T = wT + 64*96;
        prep_small<<<(64*96+64*64+255)/256, 256, 0, stream>>>(nullptr, w_mat, w1,
            nullptr, wT, w1T, 0);
        render_kernel<false><<<nblk, nthr, 0, stream>>>(rays_o, rays_d,
            nullptr, nullptr, matrixs, vectors, wT, b_mat, w1T, b1, w1, w2, b2, out, B, R);
    }
}